// Round 12
// baseline (3729.174 us; speedup 1.0000x reference)
//
#include <hip/hip_runtime.h>
#include <stdint.h>

#define NN 20000
#define NE 320000
#define DD 128
#define HH 256
#define EB 48    // edges per block, edge_iter
#define EBE 64   // edges per block, encoder

using ushort8 = __attribute__((ext_vector_type(8))) unsigned short;
using bf16x8  = __attribute__((ext_vector_type(8))) __bf16;
using floatx4 = __attribute__((ext_vector_type(4))) float;

__device__ __forceinline__ unsigned short f2bf(float f) {
  union { float f; uint32_t u; } c; c.f = f;
  uint32_t u = c.u;
  return (unsigned short)((u + 0x7FFFu + ((u >> 16) & 1u)) >> 16);
}
__device__ __forceinline__ float bf2f(unsigned short h) {
  union { uint32_t u; float f; } c; c.u = ((uint32_t)h) << 16;
  return c.f;
}
__device__ __forceinline__ bf16x8 ld_bf8(const unsigned short* p) {
  ushort8 t = *(const ushort8*)p;
  return __builtin_bit_cast(bf16x8, t);
}
__device__ __forceinline__ void split8(const float* p, bf16x8& hi, bf16x8& lo) {
  floatx4 f0 = *(const floatx4*)p;
  floatx4 f1 = *(const floatx4*)(p + 4);
  ushort8 h, l;
#pragma unroll
  for (int k = 0; k < 4; ++k) {
    unsigned short a = f2bf(f0[k]);
    h[k] = a; l[k] = f2bf(f0[k] - bf2f(a));
    unsigned short b = f2bf(f1[k]);
    h[k+4] = b; l[k+4] = f2bf(f1[k] - bf2f(b));
  }
  hi = __builtin_bit_cast(bf16x8, h);
  lo = __builtin_bit_cast(bf16x8, l);
}
__device__ __forceinline__ floatx4 MFMA3(bf16x8 ah, bf16x8 al, bf16x8 bh, bf16x8 bl, floatx4 c) {
  c = __builtin_amdgcn_mfma_f32_16x16x32_bf16(ah, bh, c, 0, 0, 0);
  c = __builtin_amdgcn_mfma_f32_16x16x32_bf16(al, bh, c, 0, 0, 0);
  c = __builtin_amdgcn_mfma_f32_16x16x32_bf16(ah, bl, c, 0, 0, 0);
  return c;
}

// ---------------- small prep kernels ----------------

__global__ void wconv_kernel(const float* __restrict__ in,
                             unsigned short* __restrict__ out_hi,
                             unsigned short* __restrict__ out_lo,
                             int K, int Nc) {
  int i = blockIdx.x * 256 + threadIdx.x;
  if (i >= K * Nc) return;
  int k = i / Nc, n = i - k * Nc;
  float v = in[i];
  unsigned short h = f2bf(v);
  out_hi[(size_t)n * K + k] = h;
  out_lo[(size_t)n * K + k] = f2bf(v - bf2f(h));
}

__global__ void xconv_kernel(const float* __restrict__ x,
                             unsigned short* __restrict__ xh, unsigned short* __restrict__ xl,
                             unsigned short* __restrict__ nh, unsigned short* __restrict__ nl) {
  int i = blockIdx.x * 256 + threadIdx.x;
  if (i < NN * DD) {
    float v = x[i];
    unsigned short h = f2bf(v), l = f2bf(v - bf2f(h));
    xh[i] = h; xl[i] = l; nh[i] = h; nl[i] = l;
  }
}

__global__ void deg_kernel(const int* __restrict__ ei, float* __restrict__ deg) {
  int e = blockIdx.x * 256 + threadIdx.x;
  if (e < NE) atomicAdd(&deg[ei[NE + e]], 1.0f);
}

__global__ void inv_kernel(const float* __restrict__ deg, float* __restrict__ idg) {
  int n = blockIdx.x * 256 + threadIdx.x;
  if (n < NN) idg[n] = 1.0f / fmaxf(deg[n], 1.0f);
}

// ---------------- per-node partial pre-activation GEMM ----------------

template<int NCH, bool USE_NF>
__launch_bounds__(256, 2)
__global__ void nodepre_kernel(
    const unsigned short* __restrict__ xh, const unsigned short* __restrict__ xl,
    const unsigned short* __restrict__ nh, const unsigned short* __restrict__ nl,
    const unsigned short* __restrict__ w0h, const unsigned short* __restrict__ w0l,
    int ko0, int st0, float* __restrict__ out0,
    const unsigned short* __restrict__ w1h, const unsigned short* __restrict__ w1l,
    int ko1, int st1, float* __restrict__ out1,
    const unsigned short* __restrict__ w2h, const unsigned short* __restrict__ w2l,
    int ko2, int st2, float* __restrict__ out2)
{
  const int y = blockIdx.y;
  const unsigned short* Wh = (y == 0) ? w0h : (y == 1) ? w1h : w2h;
  const unsigned short* Wl = (y == 0) ? w0l : (y == 1) ? w1l : w2l;
  const int ko = (y == 0) ? ko0 : (y == 1) ? ko1 : ko2;
  const int st = (y == 0) ? st0 : (y == 1) ? st1 : st2;
  float* out = (y == 0) ? out0 : (y == 1) ? out1 : out2;

  const int tid = threadIdx.x;
  const int n0 = blockIdx.x * 64;
  const int lane = tid & 63, wv = tid >> 6;
  const int lr = lane & 15, kg = lane >> 4;
  int nr[4];
#pragma unroll
  for (int rt = 0; rt < 4; ++rt) {
    const int n = n0 + rt*16 + lr;
    nr[rt] = (n < NN) ? n : (NN - 1);
  }
  const floatx4 Z4 = {0.f, 0.f, 0.f, 0.f};
  floatx4 acc[4][4];
#pragma unroll
  for (int i = 0; i < 4; ++i)
#pragma unroll
    for (int j = 0; j < 4; ++j) acc[i][j] = Z4;

#pragma unroll
  for (int ch = 0; ch < NCH; ++ch) {
    bf16x8 ah[4], al[4], bh[4], bl[4];
#pragma unroll
    for (int rt = 0; rt < 4; ++rt) {
      if (USE_NF && ch >= 4) {
        const size_t off = (size_t)nr[rt] * DD + (ch - 4)*32 + kg*8;
        ah[rt] = ld_bf8(nh + off); al[rt] = ld_bf8(nl + off);
      } else {
        const size_t off = (size_t)nr[rt] * DD + ch*32 + kg*8;
        ah[rt] = ld_bf8(xh + off); al[rt] = ld_bf8(xl + off);
      }
    }
#pragma unroll
    for (int ct = 0; ct < 4; ++ct) {
      const size_t wo = (size_t)(wv*64 + ct*16 + lr) * st + ko + ch*32 + kg*8;
      bh[ct] = ld_bf8(Wh + wo); bl[ct] = ld_bf8(Wl + wo);
    }
#pragma unroll
    for (int rt = 0; rt < 4; ++rt)
#pragma unroll
      for (int ct = 0; ct < 4; ++ct) acc[rt][ct] = MFMA3(ah[rt], al[rt], bh[ct], bl[ct], acc[rt][ct]);
  }
#pragma unroll
  for (int ct = 0; ct < 4; ++ct) {
    const int col = wv*64 + ct*16 + lr;
#pragma unroll
    for (int rt = 0; rt < 4; ++rt)
#pragma unroll
      for (int j = 0; j < 4; ++j) {
        const int n = n0 + rt*16 + kg*4 + j;
        if (n < NN) out[(size_t)n * HH + col] = acc[rt][ct][j];
      }
  }
}

// ---------------- edge encoder (psum-seeded) ----------------

__launch_bounds__(256, 2)
__global__ void encoder_kernel(
    const float* __restrict__ ea,
    const int* __restrict__ ei,
    const float* __restrict__ pes,
    const float* __restrict__ pet,
    const unsigned short* __restrict__ w1h, const unsigned short* __restrict__ w1l,
    const float* __restrict__ b1,
    const unsigned short* __restrict__ w2h, const unsigned short* __restrict__ w2l,
    const float* __restrict__ b2,
    float* __restrict__ ief32, float* __restrict__ eff32)
{
  __shared__ unsigned short h_hi[EBE * 264];
  __shared__ unsigned short h_lo[EBE * 264];
  __shared__ int sidx[EBE];
  __shared__ int tidx[EBE];
  const int tid = threadIdx.x;
  const int e0 = blockIdx.x * EBE;
  if (tid < EBE) { sidx[tid] = ei[e0 + tid]; tidx[tid] = ei[NE + e0 + tid]; }
  __syncthreads();

  const int lane = tid & 63, wv = tid >> 6;
  const int lr = lane & 15, kg = lane >> 4;
  const floatx4 Z4 = {0.f, 0.f, 0.f, 0.f};

  float pse[4][4][4];
#pragma unroll
  for (int rt = 0; rt < 4; ++rt)
#pragma unroll
    for (int j = 0; j < 4; ++j) {
      const int row = rt*16 + kg*4 + j;
      const float* ps = pes + (size_t)sidx[row] * HH;
      const float* pt = pet + (size_t)tidx[row] * HH;
#pragma unroll
      for (int ct = 0; ct < 4; ++ct) {
        const int col = wv*64 + ct*16 + lr;
        pse[rt][j][ct] = ps[col] + pt[col];
      }
    }

  floatx4 acc[4][4];
#pragma unroll
  for (int i = 0; i < 4; ++i)
#pragma unroll
    for (int j = 0; j < 4; ++j) acc[i][j] = Z4;
#pragma unroll
  for (int sub = 0; sub < 4; ++sub) {
    const int off = sub*32 + kg*8;
    bf16x8 ah[4], al[4], bh[4], bl[4];
#pragma unroll
    for (int rt = 0; rt < 4; ++rt)
      split8(ea + (size_t)(e0 + rt*16 + lr) * DD + off, ah[rt], al[rt]);
#pragma unroll
    for (int ct = 0; ct < 4; ++ct) {
      const size_t wo = (size_t)(wv*64 + ct*16 + lr) * 384 + 256 + off;
      bh[ct] = ld_bf8(w1h + wo); bl[ct] = ld_bf8(w1l + wo);
    }
#pragma unroll
    for (int rt = 0; rt < 4; ++rt)
#pragma unroll
      for (int ct = 0; ct < 4; ++ct) acc[rt][ct] = MFMA3(ah[rt], al[rt], bh[ct], bl[ct], acc[rt][ct]);
  }
#pragma unroll
  for (int ct = 0; ct < 4; ++ct) {
    const int col = wv*64 + ct*16 + lr;
    const float bias = b1[col];
#pragma unroll
    for (int rt = 0; rt < 4; ++rt)
#pragma unroll
      for (int j = 0; j < 4; ++j) {
        const float v = fmaxf(acc[rt][ct][j] + bias + pse[rt][j][ct], 0.f);
        const unsigned short hh = f2bf(v);
        const int idx = (rt*16 + kg*4 + j) * 264 + col;
        h_hi[idx] = hh;
        h_lo[idx] = f2bf(v - bf2f(hh));
      }
  }
  __syncthreads();

  floatx4 acc2[4][2];
#pragma unroll
  for (int i = 0; i < 4; ++i) { acc2[i][0] = Z4; acc2[i][1] = Z4; }
#pragma unroll
  for (int ch = 0; ch < 8; ++ch) {
    bf16x8 ah[4], al[4], bh[2], bl[2];
#pragma unroll
    for (int rt = 0; rt < 4; ++rt) {
      const int idx = (rt*16 + lr) * 264 + ch*32 + kg*8;
      ah[rt] = ld_bf8(&h_hi[idx]); al[rt] = ld_bf8(&h_lo[idx]);
    }
#pragma unroll
    for (int c2 = 0; c2 < 2; ++c2) {
      const size_t wo = (size_t)(wv*32 + c2*16 + lr) * 256 + ch*32 + kg*8;
      bh[c2] = ld_bf8(w2h + wo); bl[c2] = ld_bf8(w2l + wo);
    }
#pragma unroll
    for (int rt = 0; rt < 4; ++rt)
#pragma unroll
      for (int c2 = 0; c2 < 2; ++c2) acc2[rt][c2] = MFMA3(ah[rt], al[rt], bh[c2], bl[c2], acc2[rt][c2]);
  }
#pragma unroll
  for (int c2 = 0; c2 < 2; ++c2) {
    const int col = wv*32 + c2*16 + lr;
    const float bias = b2[col];
#pragma unroll
    for (int rt = 0; rt < 4; ++rt)
#pragma unroll
      for (int j = 0; j < 4; ++j) {
        const float fv = acc2[rt][c2][j] + bias;
        const size_t idx = (size_t)(e0 + rt*16 + kg*4 + j) * DD + col;
        ief32[idx] = fv;
        eff32[idx] = fv;
      }
  }
}

// ---------------- fused per-iteration edge kernel ----------------
// Single shared hi/lo buffer pair, time-shared: h_edge (stride 264) -> eraw
// (stride 136) -> h_msg (stride 264), with barriers between tenants.
// 51 KB LDS -> 3 blocks/CU.

__launch_bounds__(256, 3)
__global__ void edge_iter_kernel(
    const float* __restrict__ ief32,
    float* __restrict__ eff32,
    const int* __restrict__ ei,
    const float* __restrict__ pse_,
    const float* __restrict__ pte_,
    const float* __restrict__ psm_,
    const unsigned short* __restrict__ ew1h, const unsigned short* __restrict__ ew1l,
    const float* __restrict__ eb1,
    const unsigned short* __restrict__ ew2h, const unsigned short* __restrict__ ew2l,
    const float* __restrict__ eb2,
    const unsigned short* __restrict__ mw1h, const unsigned short* __restrict__ mw1l,
    const float* __restrict__ mb1,
    const unsigned short* __restrict__ mw2h, const unsigned short* __restrict__ mw2l,
    const float* __restrict__ mb2,
    const float* __restrict__ lng, const float* __restrict__ lnb,
    float* __restrict__ agg,
    float* __restrict__ out_edge,
    int write_out)
{
  __shared__ unsigned short bufh[EB * 264];
  __shared__ unsigned short bufl[EB * 264];
  __shared__ int sidx[EB];
  __shared__ int tidx[EB];

  const int tid = threadIdx.x;
  const int e0 = blockIdx.x * EB;
  if (tid < EB) {
    const int e = e0 + tid;
    const int ec = (e < NE) ? e : (NE - 1);
    sidx[tid] = ei[ec];
    tidx[tid] = ei[NE + ec];
  }
  __syncthreads();

  const int lane = tid & 63, wv = tid >> 6;
  const int lr = lane & 15, kg = lane >> 4;
  int erow_c[3];
#pragma unroll
  for (int rt = 0; rt < 3; ++rt) {
    const int er = e0 + rt*16 + lr;
    erow_c[rt] = (er < NE) ? er : (NE - 1);
  }
  const floatx4 Z4 = {0.f, 0.f, 0.f, 0.f};

  // ===== psum gathers (edge-MLP seed) =====
  float pse[3][4][4];
#pragma unroll
  for (int rt = 0; rt < 3; ++rt)
#pragma unroll
    for (int j = 0; j < 4; ++j) {
      const int row = rt*16 + kg*4 + j;
      const float* ps = pse_ + (size_t)sidx[row] * HH;
      const float* pt = pte_ + (size_t)tidx[row] * HH;
#pragma unroll
      for (int ct = 0; ct < 4; ++ct) {
        const int col = wv*64 + ct*16 + lr;
        pse[rt][j][ct] = ps[col] + pt[col];
      }
    }

  // ===== P2: edge MLP layer 1, edge_c part (K=256: ie | ef) =====
  floatx4 acc[3][4];
#pragma unroll
  for (int i = 0; i < 3; ++i)
#pragma unroll
    for (int j = 0; j < 4; ++j) acc[i][j] = Z4;

#pragma unroll
  for (int seg = 0; seg < 2; ++seg) {
    const float* fb[3];
#pragma unroll
    for (int rt = 0; rt < 3; ++rt) {
      const size_t e = (size_t)erow_c[rt] * DD;
      fb[rt] = (seg == 0) ? ief32 + e : eff32 + e;
    }
#pragma unroll
    for (int sub = 0; sub < 4; ++sub) {
      const int off = sub*32 + kg*8;
      bf16x8 ah[3], al[3], bh[4], bl[4];
#pragma unroll
      for (int rt = 0; rt < 3; ++rt) split8(fb[rt] + off, ah[rt], al[rt]);
#pragma unroll
      for (int ct = 0; ct < 4; ++ct) {
        const size_t wo = (size_t)(wv*64 + ct*16 + lr) * 768 + 512 + seg*128 + off;
        bh[ct] = ld_bf8(ew1h + wo); bl[ct] = ld_bf8(ew1l + wo);
      }
#pragma unroll
      for (int rt = 0; rt < 3; ++rt)
#pragma unroll
        for (int ct = 0; ct < 4; ++ct) acc[rt][ct] = MFMA3(ah[rt], al[rt], bh[ct], bl[ct], acc[rt][ct]);
    }
  }
  // h_edge write (stride 264)
#pragma unroll
  for (int ct = 0; ct < 4; ++ct) {
    const int col = wv*64 + ct*16 + lr;
    const float bias = eb1[col];
#pragma unroll
    for (int rt = 0; rt < 3; ++rt)
#pragma unroll
      for (int j = 0; j < 4; ++j) {
        const float v = fmaxf(acc[rt][ct][j] + bias + pse[rt][j][ct], 0.f);
        const unsigned short hh = f2bf(v);
        const int idx = (rt*16 + kg*4 + j) * 264 + col;
        bufh[idx] = hh;
        bufl[idx] = f2bf(v - bf2f(hh));
      }
  }
  __syncthreads();   // h_edge visible

  // ===== P5: edge MLP layer 2 (reads h_edge) -> acc2 registers =====
  floatx4 acc2[3][2];
#pragma unroll
  for (int i = 0; i < 3; ++i) { acc2[i][0] = Z4; acc2[i][1] = Z4; }
#pragma unroll
  for (int ch = 0; ch < 8; ++ch) {
    bf16x8 ah[3], al[3], bh[2], bl[2];
#pragma unroll
    for (int rt = 0; rt < 3; ++rt) {
      const int idx = (rt*16 + lr) * 264 + ch*32 + kg*8;
      ah[rt] = ld_bf8(&bufh[idx]); al[rt] = ld_bf8(&bufl[idx]);
    }
#pragma unroll
    for (int c2 = 0; c2 < 2; ++c2) {
      const size_t wo = (size_t)(wv*32 + c2*16 + lr) * 256 + ch*32 + kg*8;
      bh[c2] = ld_bf8(ew2h + wo); bl[c2] = ld_bf8(ew2l + wo);
    }
#pragma unroll
    for (int rt = 0; rt < 3; ++rt)
#pragma unroll
      for (int c2 = 0; c2 < 2; ++c2) acc2[rt][c2] = MFMA3(ah[rt], al[rt], bh[c2], bl[c2], acc2[rt][c2]);
  }
  __syncthreads();   // all h_edge reads done; buffer free

  // eraw write (stride 136)
#pragma unroll
  for (int c2 = 0; c2 < 2; ++c2) {
    const int col = wv*32 + c2*16 + lr;
    const float bias = eb2[col];
#pragma unroll
    for (int rt = 0; rt < 3; ++rt)
#pragma unroll
      for (int j = 0; j < 4; ++j) {
        const float v = acc2[rt][c2][j] + bias;
        const unsigned short hh = f2bf(v);
        const int idx = (rt*16 + kg*4 + j) * 136 + col;
        bufh[idx] = hh;
        bufl[idx] = f2bf(v - bf2f(hh));
      }
  }
  __syncthreads();   // eraw visible

  // ===== P6: msg MLP layer 1, eraw part (K=128) + psrc_m seed =====
  float psm[3][4][4];
#pragma unroll
  for (int rt = 0; rt < 3; ++rt)
#pragma unroll
    for (int j = 0; j < 4; ++j) {
      const int row = rt*16 + kg*4 + j;
      const float* ps = psm_ + (size_t)sidx[row] * HH;
#pragma unroll
      for (int ct = 0; ct < 4; ++ct)
        psm[rt][j][ct] = ps[wv*64 + ct*16 + lr];
    }

  floatx4 accm[3][4];
#pragma unroll
  for (int i = 0; i < 3; ++i)
#pragma unroll
    for (int j = 0; j < 4; ++j) accm[i][j] = Z4;
#pragma unroll
  for (int sub = 0; sub < 4; ++sub) {
    const int off = sub*32 + kg*8;
    bf16x8 ah[3], al[3], bh[4], bl[4];
#pragma unroll
    for (int rt = 0; rt < 3; ++rt) {
      const int idx = (rt*16 + lr) * 136 + off;
      ah[rt] = ld_bf8(&bufh[idx]); al[rt] = ld_bf8(&bufl[idx]);
    }
#pragma unroll
    for (int ct = 0; ct < 4; ++ct) {
      const size_t wo = (size_t)(wv*64 + ct*16 + lr) * 384 + 256 + off;
      bh[ct] = ld_bf8(mw1h + wo); bl[ct] = ld_bf8(mw1l + wo);
    }
#pragma unroll
    for (int rt = 0; rt < 3; ++rt)
#pragma unroll
      for (int ct = 0; ct < 4; ++ct) accm[rt][ct] = MFMA3(ah[rt], al[rt], bh[ct], bl[ct], accm[rt][ct]);
  }

  // ===== residual + LayerNorm (reads eraw from LDS + ief32) -> eff32 (+ d_out) =====
  if (tid < EB * 4) {
    const int row = tid >> 2, sub = tid & 3;
    const int er = e0 + row;
    if (er < NE) {
      const size_t e = (size_t)er;
      float v[32];
      float s = 0.f, ss = 0.f;
#pragma unroll
      for (int c8 = 0; c8 < 4; ++c8) {
        const int li = row * 136 + sub*32 + c8*8;
        ushort8 rh = *(const ushort8*)&bufh[li];
        ushort8 rl = *(const ushort8*)&bufl[li];
        const float* ip = &ief32[e * DD + sub*32 + c8*8];
        floatx4 i0 = *(const floatx4*)ip;
        floatx4 i1 = *(const floatx4*)(ip + 4);
#pragma unroll
        for (int k = 0; k < 4; ++k) {
          float v0 = (bf2f(rh[k]) + bf2f(rl[k])) + i0[k];
          float v1 = (bf2f(rh[k+4]) + bf2f(rl[k+4])) + i1[k];
          v[c8*8 + k] = v0; v[c8*8 + 4 + k] = v1;
          s += v0 + v1; ss += v0*v0 + v1*v1;
        }
      }
      s  += __shfl_xor(s, 1);  s  += __shfl_xor(s, 2);
      ss += __shfl_xor(ss, 1); ss += __shfl_xor(ss, 2);
      const float mu  = s * (1.f/128.f);
      const float var = ss * (1.f/128.f) - mu * mu;
      const float inv = rsqrtf(fmaxf(var, 0.f) + 1e-5f);
#pragma unroll
      for (int c8 = 0; c8 < 4; ++c8) {
        floatx4 o0, o1;
#pragma unroll
        for (int k = 0; k < 8; ++k) {
          const int col = sub*32 + c8*8 + k;
          const float o = (v[c8*8 + k] - mu) * inv * lng[col] + lnb[col];
          if (k < 4) o0[k] = o; else o1[k-4] = o;
        }
        *(floatx4*)&eff32[e * DD + sub*32 + c8*8] = o0;
        *(floatx4*)&eff32[e * DD + sub*32 + c8*8 + 4] = o1;
        if (write_out) {
          *(floatx4*)&out_edge[e * DD + sub*32 + c8*8] = o0;
          *(floatx4*)&out_edge[e * DD + sub*32 + c8*8 + 4] = o1;
        }
      }
    }
  }
  __syncthreads();   // all eraw reads (P6 + LN) done; buffer free

  // h_msg write (stride 264)
#pragma unroll
  for (int ct = 0; ct < 4; ++ct) {
    const int col = wv*64 + ct*16 + lr;
    const float bias = mb1[col];
#pragma unroll
    for (int rt = 0; rt < 3; ++rt)
#pragma unroll
      for (int j = 0; j < 4; ++j) {
        const float v = fmaxf(accm[rt][ct][j] + bias + psm[rt][j][ct], 0.f);
        const unsigned short hh = f2bf(v);
        const int idx = (rt*16 + kg*4 + j) * 264 + col;
        bufh[idx] = hh;
        bufl[idx] = f2bf(v - bf2f(hh));
      }
  }
  __syncthreads();   // h_msg visible

  // ===== P7: msg MLP layer 2 + atomic scatter =====
  floatx4 accq[3][2];
#pragma unroll
  for (int i = 0; i < 3; ++i) { accq[i][0] = Z4; accq[i][1] = Z4; }
#pragma unroll
  for (int ch = 0; ch < 8; ++ch) {
    bf16x8 ah[3], al[3], bh[2], bl[2];
#pragma unroll
    for (int rt = 0; rt < 3; ++rt) {
      const int idx = (rt*16 + lr) * 264 + ch*32 + kg*8;
      ah[rt] = ld_bf8(&bufh[idx]); al[rt] = ld_bf8(&bufl[idx]);
    }
#pragma unroll
    for (int c2 = 0; c2 < 2; ++c2) {
      const size_t wo = (size_t)(wv*32 + c2*16 + lr) * 256 + ch*32 + kg*8;
      bh[c2] = ld_bf8(mw2h + wo); bl[c2] = ld_bf8(mw2l + wo);
    }
#pragma unroll
    for (int rt = 0; rt < 3; ++rt)
#pragma unroll
      for (int c2 = 0; c2 < 2; ++c2) accq[rt][c2] = MFMA3(ah[rt], al[rt], bh[c2], bl[c2], accq[rt][c2]);
  }
#pragma unroll
  for (int c2 = 0; c2 < 2; ++c2) {
    const int col = wv*32 + c2*16 + lr;
    const float bias = mb2[col];
#pragma unroll
    for (int rt = 0; rt < 3; ++rt)
#pragma unroll
      for (int j = 0; j < 4; ++j) {
        const int row = rt*16 + kg*4 + j;
        if (e0 + row < NE)
          atomicAdd(&agg[(size_t)tidx[row] * DD + col], accq[rt][c2][j] + bias);
      }
  }
}

// ---------------- node update ----------------

__launch_bounds__(256, 2)
__global__ void node_update_kernel(
    const float* __restrict__ agg, const float* __restrict__ idg,
    const unsigned short* __restrict__ nwh, const unsigned short* __restrict__ nwl,
    const float* __restrict__ nb,
    const float* __restrict__ x,
    const float* __restrict__ lng, const float* __restrict__ lnb,
    float* __restrict__ out_node,
    unsigned short* __restrict__ nh, unsigned short* __restrict__ nl,
    int write_out)
{
  __shared__ unsigned short a_hi[64 * 136];
  __shared__ unsigned short a_lo[64 * 136];
  __shared__ float o_lds[64 * 132];
  const int tid = threadIdx.x;
  const int n0 = blockIdx.x * 64;
  const int row = tid >> 2, sub = tid & 3;
  const int n = n0 + row;
  {
    const float s = (n < NN) ? idg[n] : 0.f;
#pragma unroll
    for (int c4 = 0; c4 < 8; ++c4) {
      floatx4 v = {0.f, 0.f, 0.f, 0.f};
      if (n < NN) v = *(const floatx4*)&agg[(size_t)n * DD + sub*32 + c4*4];
#pragma unroll
      for (int k = 0; k < 4; ++k) {
        const float f = v[k] * s;
        const unsigned short hh = f2bf(f);
        const int idx = row * 136 + sub*32 + c4*4 + k;
        a_hi[idx] = hh;
        a_lo[idx] = f2bf(f - bf2f(hh));
      }
    }
  }
  __syncthreads();

  const int lane = tid & 63, wv = tid >> 6;
  const int lr = lane & 15, kg = lane >> 4;
  const floatx4 Z4 = {0.f, 0.f, 0.f, 0.f};
  floatx4 acc[4][2];
#pragma unroll
  for (int i = 0; i < 4; ++i) { acc[i][0] = Z4; acc[i][1] = Z4; }
#pragma unroll
  for (int ch = 0; ch < 4; ++ch) {
    bf16x8 ah[4], al[4], bh[2], bl[2];
#pragma unroll
    for (int rt = 0; rt < 4; ++rt) {
      const int idx = (rt*16 + lr) * 136 + ch*32 + kg*8;
      ah[rt] = ld_bf8(&a_hi[idx]); al[rt] = ld_bf8(&a_lo[idx]);
    }
#pragma unroll
    for (int c2 = 0; c2 < 2; ++c2) {
      const size_t wo = (size_t)(wv*32 + c2*16 + lr) * DD + ch*32 + kg*8;
      bh[c2] = ld_bf8(nwh + wo); bl[c2] = ld_bf8(nwl + wo);
    }
#pragma unroll
    for (int rt = 0; rt < 4; ++rt)
#pragma unroll
      for (int c2 = 0; c2 < 2; ++c2) acc[rt][c2] = MFMA3(ah[rt], al[rt], bh[c2], bl[c2], acc[rt][c2]);
  }
#pragma unroll
  for (int c2 = 0; c2 < 2; ++c2) {
    const int col = wv*32 + c2*16 + lr;
    const float bias = nb[col];
#pragma unroll
    for (int rt = 0; rt < 4; ++rt)
#pragma unroll
      for (int j = 0; j < 4; ++j)
        o_lds[(rt*16 + kg*4 + j) * 132 + col] = acc[rt][c2][j] + bias;
  }
  __syncthreads();

  if (n < NN) {
    float v[32];
    float s = 0.f, ss = 0.f;
#pragma unroll
    for (int c4 = 0; c4 < 8; ++c4) {
      floatx4 xa = *(const floatx4*)&x[(size_t)n * DD + sub*32 + c4*4];
#pragma unroll
      for (int k = 0; k < 4; ++k) {
        const float val = o_lds[row * 132 + sub*32 + c4*4 + k] + xa[k];
        v[c4*4 + k] = val; s += val; ss += val * val;
      }
    }
    s  += __shfl_xor(s, 1);  s  += __shfl_xor(s, 2);
    ss += __shfl_xor(ss, 1); ss += __shfl_xor(ss, 2);
    const float mu  = s * (1.f/128.f);
    const float var = ss * (1.f/128.f) - mu * mu;
    const float inv = rsqrtf(fmaxf(var, 0.f) + 1e-5f);
#pragma unroll
    for (int c8 = 0; c8 < 4; ++c8) {
      floatx4 o0, o1; ushort8 oh, ol;
#pragma unroll
      for (int k = 0; k < 8; ++k) {
        const int col = sub*32 + c8*8 + k;
        const float o = (v[c8*8 + k] - mu) * inv * lng[col] + lnb[col];
        if (k < 4) o0[k] = o; else o1[k-4] = o;
        const unsigned short hh = f2bf(o);
        oh[k] = hh;
        ol[k] = f2bf(o - bf2f(hh));
      }
      if (write_out) {
        *(floatx4*)&out_node[(size_t)n * DD + sub*32 + c8*8] = o0;
        *(floatx4*)&out_node[(size_t)n * DD + sub*32 + c8*8 + 4] = o1;
      }
      *(ushort8*)&nh[(size_t)n * DD + sub*32 + c8*8] = oh;
      *(ushort8*)&nl[(size_t)n * DD + sub*32 + c8*8] = ol;
    }
  }
}

// ---------------- host launch ----------------

extern "C" void kernel_launch(void* const* d_in, const int* in_sizes, int n_in,
                              void* d_out, int out_size, void* d_ws, size_t ws_size,
                              hipStream_t stream) {
  (void)in_sizes; (void)n_in; (void)out_size; (void)ws_size;

  const float* x      = (const float*)d_in[0];
  const float* ea     = (const float*)d_in[1];
  const int*   ei     = (const int*)d_in[2];
  const float* enc_w1 = (const float*)d_in[3];
  const float* enc_b1 = (const float*)d_in[4];
  const float* enc_w2 = (const float*)d_in[5];
  const float* enc_b2 = (const float*)d_in[6];
  const float* em_w1  = (const float*)d_in[7];
  const float* em_b1  = (const float*)d_in[8];
  const float* em_w2  = (const float*)d_in[9];
  const float* em_b2  = (const float*)d_in[10];
  const float* nm_w1  = (const float*)d_in[11];
  const float* nm_b1  = (const float*)d_in[12];
  const float* nm_w2  = (const float*)d_in[13];
  const float* nm_b2  = (const float*)d_in[14];
  const float* no_w   = (const float*)d_in[15];
  const float* no_b   = (const float*)d_in[16];
  const float* nlng   = (const float*)d_in[17];
  const float* nlnb   = (const float*)d_in[18];
  const float* elng   = (const float*)d_in[19];
  const float* elnb   = (const float*)d_in[20];

  float* out_node = (float*)d_out;
  float* ief32    = out_node + (size_t)NN * DD;  // f32 init_edge; final edge output overwrites

  char* p = (char*)d_ws;
  auto alloc = [&](size_t bytes) -> void* {
    void* r = (void*)p;
    p += (bytes + 255) & ~(size_t)255;
    return r;
  };
  unsigned short* xb_h = (unsigned short*)alloc((size_t)NN * DD * 2);
  unsigned short* xb_l = (unsigned short*)alloc((size_t)NN * DD * 2);
  unsigned short* nf_h = (unsigned short*)alloc((size_t)NN * DD * 2);
  unsigned short* nf_l = (unsigned short*)alloc((size_t)NN * DD * 2);
  float*          eff32 = (float*)alloc((size_t)NE * DD * 4);
  float*          agg  = (float*)alloc((size_t)NN * DD * 4);
  float*          deg  = (float*)alloc((size_t)NN * 4);
  float*          idg  = (float*)alloc((size_t)NN * 4);
  float*          psrc_e = (float*)alloc((size_t)NN * HH * 4);
  float*          ptgt_e = (float*)alloc((size_t)NN * HH * 4);
  float*          psrc_m = (float*)alloc((size_t)NN * HH * 4);
  unsigned short* cw1h = (unsigned short*)alloc((size_t)384 * 256 * 2);
  unsigned short* cw1l = (unsigned short*)alloc((size_t)384 * 256 * 2);
  unsigned short* cw2h = (unsigned short*)alloc((size_t)256 * 128 * 2);
  unsigned short* cw2l = (unsigned short*)alloc((size_t)256 * 128 * 2);
  unsigned short* ew1h = (unsigned short*)alloc((size_t)768 * 256 * 2);
  unsigned short* ew1l = (unsigned short*)alloc((size_t)768 * 256 * 2);
  unsigned short* ew2h = (unsigned short*)alloc((size_t)256 * 128 * 2);
  unsigned short* ew2l = (unsigned short*)alloc((size_t)256 * 128 * 2);
  unsigned short* mw1h = (unsigned short*)alloc((size_t)384 * 256 * 2);
  unsigned short* mw1l = (unsigned short*)alloc((size_t)384 * 256 * 2);
  unsigned short* mw2h = (unsigned short*)alloc((size_t)256 * 128 * 2);
  unsigned short* mw2l = (unsigned short*)alloc((size_t)256 * 128 * 2);
  unsigned short* nwh  = (unsigned short*)alloc((size_t)128 * 128 * 2);
  unsigned short* nwl  = (unsigned short*)alloc((size_t)128 * 128 * 2);

  wconv_kernel<<<(384*256 + 255)/256, 256, 0, stream>>>(enc_w1, cw1h, cw1l, 384, 256);
  wconv_kernel<<<(256*128 + 255)/256, 256, 0, stream>>>(enc_w2, cw2h, cw2l, 256, 128);
  wconv_kernel<<<(768*256 + 255)/256, 256, 0, stream>>>(em_w1, ew1h, ew1l, 768, 256);
  wconv_kernel<<<(256*128 + 255)/256, 256, 0, stream>>>(em_w2, ew2h, ew2l, 256, 128);
  wconv_kernel<<<(384*256 + 255)/256, 256, 0, stream>>>(nm_w1, mw1h, mw1l, 384, 256);
  wconv_kernel<<<(256*128 + 255)/256, 256, 0, stream>>>(nm_w2, mw2h, mw2l, 256, 128);
  wconv_kernel<<<(128*128 + 255)/256, 256, 0, stream>>>(no_w, nwh, nwl, 128, 128);

  xconv_kernel<<<(NN*DD + 255)/256, 256, 0, stream>>>(x, xb_h, xb_l, nf_h, nf_l);

  hipMemsetAsync(deg, 0, (size_t)NN * 4, stream);
  deg_kernel<<<(NE + 255)/256, 256, 0, stream>>>(ei, deg);
  inv_kernel<<<(NN + 255)/256, 256, 0, stream>>>(deg, idg);

  nodepre_kernel<4, false><<<dim3(313, 2), 256, 0, stream>>>(
      xb_h, xb_l, nf_h, nf_l,
      cw1h, cw1l, 0,   384, psrc_e,
      cw1h, cw1l, 128, 384, ptgt_e,
      cw1h, cw1l, 0,   384, psrc_e);

  encoder_kernel<<<NE/EBE, 256, 0, stream>>>(ea, ei, psrc_e, ptgt_e,
                                             cw1h, cw1l, enc_b1, cw2h, cw2l, enc_b2,
                                             ief32, eff32);

  const int egrid = (NE + EB - 1) / EB;
  for (int it = 0; it < 3; ++it) {
    const int last = (it == 2) ? 1 : 0;
    nodepre_kernel<8, true><<<dim3(313, 3), 256, 0, stream>>>(
        xb_h, xb_l, nf_h, nf_l,
        ew1h, ew1l, 0,   768, psrc_e,
        ew1h, ew1l, 256, 768, ptgt_e,
        mw1h, mw1l, 0,   384, psrc_m);
    hipMemsetAsync(agg, 0, (size_t)NN * DD * 4, stream);
    edge_iter_kernel<<<egrid, 256, 0, stream>>>(
        ief32, eff32, ei, psrc_e, ptgt_e, psrc_m,
        ew1h, ew1l, em_b1, ew2h, ew2l, em_b2,
        mw1h, mw1l, nm_b1, mw2h, mw2l, nm_b2,
        elng, elnb, agg, ief32, last);
    node_update_kernel<<<(NN + 63)/64, 256, 0, stream>>>(
        agg, idg, nwh, nwl, no_b, x, nlng, nlnb, out_node, nf_h, nf_l, last);
  }
}

// Round 13
// 3449.797 us; speedup vs baseline: 1.0810x; 1.0810x over previous
//
#include <hip/hip_runtime.h>
#include <stdint.h>

#define NN 20000
#define NE 320000
#define DD 128
#define HH 256
#define EB 48    // edges per block, edge_iter
#define EBE 64   // edges per block, encoder

using ushort8 = __attribute__((ext_vector_type(8))) unsigned short;
using bf16x8  = __attribute__((ext_vector_type(8))) __bf16;
using floatx4 = __attribute__((ext_vector_type(4))) float;

__device__ __forceinline__ unsigned short f2bf(float f) {
  union { float f; uint32_t u; } c; c.f = f;
  uint32_t u = c.u;
  return (unsigned short)((u + 0x7FFFu + ((u >> 16) & 1u)) >> 16);
}
__device__ __forceinline__ float bf2f(unsigned short h) {
  union { uint32_t u; float f; } c; c.u = ((uint32_t)h) << 16;
  return c.f;
}
__device__ __forceinline__ bf16x8 ld_bf8(const unsigned short* p) {
  ushort8 t = *(const ushort8*)p;
  return __builtin_bit_cast(bf16x8, t);
}
__device__ __forceinline__ void split8(const float* p, bf16x8& hi, bf16x8& lo) {
  floatx4 f0 = *(const floatx4*)p;
  floatx4 f1 = *(const floatx4*)(p + 4);
  ushort8 h, l;
#pragma unroll
  for (int k = 0; k < 4; ++k) {
    unsigned short a = f2bf(f0[k]);
    h[k] = a; l[k] = f2bf(f0[k] - bf2f(a));
    unsigned short b = f2bf(f1[k]);
    h[k+4] = b; l[k+4] = f2bf(f1[k] - bf2f(b));
  }
  hi = __builtin_bit_cast(bf16x8, h);
  lo = __builtin_bit_cast(bf16x8, l);
}
__device__ __forceinline__ floatx4 MFMA3(bf16x8 ah, bf16x8 al, bf16x8 bh, bf16x8 bl, floatx4 c) {
  c = __builtin_amdgcn_mfma_f32_16x16x32_bf16(ah, bh, c, 0, 0, 0);
  c = __builtin_amdgcn_mfma_f32_16x16x32_bf16(al, bh, c, 0, 0, 0);
  c = __builtin_amdgcn_mfma_f32_16x16x32_bf16(ah, bl, c, 0, 0, 0);
  return c;
}

// ---------------- small prep kernels ----------------

__global__ void wconv_kernel(const float* __restrict__ in,
                             unsigned short* __restrict__ out_hi,
                             unsigned short* __restrict__ out_lo,
                             int K, int Nc) {
  int i = blockIdx.x * 256 + threadIdx.x;
  if (i >= K * Nc) return;
  int k = i / Nc, n = i - k * Nc;
  float v = in[i];
  unsigned short h = f2bf(v);
  out_hi[(size_t)n * K + k] = h;
  out_lo[(size_t)n * K + k] = f2bf(v - bf2f(h));
}

__global__ void xconv_kernel(const float* __restrict__ x,
                             unsigned short* __restrict__ xh, unsigned short* __restrict__ xl,
                             unsigned short* __restrict__ nh, unsigned short* __restrict__ nl) {
  int i = blockIdx.x * 256 + threadIdx.x;
  if (i < NN * DD) {
    float v = x[i];
    unsigned short h = f2bf(v), l = f2bf(v - bf2f(h));
    xh[i] = h; xl[i] = l; nh[i] = h; nl[i] = l;
  }
}

__global__ void deg_kernel(const int* __restrict__ ei, float* __restrict__ deg) {
  int e = blockIdx.x * 256 + threadIdx.x;
  if (e < NE) atomicAdd(&deg[ei[NE + e]], 1.0f);
}

__global__ void inv_kernel(const float* __restrict__ deg, float* __restrict__ idg) {
  int n = blockIdx.x * 256 + threadIdx.x;
  if (n < NN) idg[n] = 1.0f / fmaxf(deg[n], 1.0f);
}

// ---------------- per-node partial pre-activation GEMM ----------------
// psum layout (vectorized for edge-kernel gathers):
//   addr = n*256 + wv*64 + lr*4 + ct   where col = wv*64 + ct*16 + lr

template<int NCH, bool USE_NF>
__launch_bounds__(256, 2)
__global__ void nodepre_kernel(
    const unsigned short* __restrict__ xh, const unsigned short* __restrict__ xl,
    const unsigned short* __restrict__ nh, const unsigned short* __restrict__ nl,
    const unsigned short* __restrict__ w0h, const unsigned short* __restrict__ w0l,
    int ko0, int st0, float* __restrict__ out0,
    const unsigned short* __restrict__ w1h, const unsigned short* __restrict__ w1l,
    int ko1, int st1, float* __restrict__ out1,
    const unsigned short* __restrict__ w2h, const unsigned short* __restrict__ w2l,
    int ko2, int st2, float* __restrict__ out2)
{
  const int y = blockIdx.y;
  const unsigned short* Wh = (y == 0) ? w0h : (y == 1) ? w1h : w2h;
  const unsigned short* Wl = (y == 0) ? w0l : (y == 1) ? w1l : w2l;
  const int ko = (y == 0) ? ko0 : (y == 1) ? ko1 : ko2;
  const int st = (y == 0) ? st0 : (y == 1) ? st1 : st2;
  float* out = (y == 0) ? out0 : (y == 1) ? out1 : out2;

  const int tid = threadIdx.x;
  const int n0 = blockIdx.x * 64;
  const int lane = tid & 63, wv = tid >> 6;
  const int lr = lane & 15, kg = lane >> 4;
  int nr[4];
#pragma unroll
  for (int rt = 0; rt < 4; ++rt) {
    const int n = n0 + rt*16 + lr;
    nr[rt] = (n < NN) ? n : (NN - 1);
  }
  const floatx4 Z4 = {0.f, 0.f, 0.f, 0.f};
  floatx4 acc[4][4];
#pragma unroll
  for (int i = 0; i < 4; ++i)
#pragma unroll
    for (int j = 0; j < 4; ++j) acc[i][j] = Z4;

#pragma unroll
  for (int ch = 0; ch < NCH; ++ch) {
    bf16x8 ah[4], al[4], bh[4], bl[4];
#pragma unroll
    for (int rt = 0; rt < 4; ++rt) {
      if (USE_NF && ch >= 4) {
        const size_t off = (size_t)nr[rt] * DD + (ch - 4)*32 + kg*8;
        ah[rt] = ld_bf8(nh + off); al[rt] = ld_bf8(nl + off);
      } else {
        const size_t off = (size_t)nr[rt] * DD + ch*32 + kg*8;
        ah[rt] = ld_bf8(xh + off); al[rt] = ld_bf8(xl + off);
      }
    }
#pragma unroll
    for (int ct = 0; ct < 4; ++ct) {
      const size_t wo = (size_t)(wv*64 + ct*16 + lr) * st + ko + ch*32 + kg*8;
      bh[ct] = ld_bf8(Wh + wo); bl[ct] = ld_bf8(Wl + wo);
    }
#pragma unroll
    for (int rt = 0; rt < 4; ++rt)
#pragma unroll
      for (int ct = 0; ct < 4; ++ct) acc[rt][ct] = MFMA3(ah[rt], al[rt], bh[ct], bl[ct], acc[rt][ct]);
  }
  // transposed-psum write: addr = n*256 + wv*64 + lr'*4 + ct, where col = wv*64 + ct*16 + lr'
#pragma unroll
  for (int ct = 0; ct < 4; ++ct) {
#pragma unroll
    for (int rt = 0; rt < 4; ++rt)
#pragma unroll
      for (int j = 0; j < 4; ++j) {
        const int n = n0 + rt*16 + kg*4 + j;
        if (n < NN) out[(size_t)n * HH + wv*64 + lr*4 + ct] = acc[rt][ct][j];
      }
  }
}

// ---------------- edge encoder (psum-seeded, vectorized gathers) ----------------

__launch_bounds__(256, 2)
__global__ void encoder_kernel(
    const float* __restrict__ ea,
    const int* __restrict__ ei,
    const float* __restrict__ pes,
    const float* __restrict__ pet,
    const unsigned short* __restrict__ w1h, const unsigned short* __restrict__ w1l,
    const float* __restrict__ b1,
    const unsigned short* __restrict__ w2h, const unsigned short* __restrict__ w2l,
    const float* __restrict__ b2,
    float* __restrict__ ief32, float* __restrict__ eff32)
{
  __shared__ unsigned short h_hi[EBE * 264];
  __shared__ unsigned short h_lo[EBE * 264];
  __shared__ int sidx[EBE];
  __shared__ int tidx[EBE];
  const int tid = threadIdx.x;
  const int e0 = blockIdx.x * EBE;
  if (tid < EBE) { sidx[tid] = ei[e0 + tid]; tidx[tid] = ei[NE + e0 + tid]; }
  __syncthreads();

  const int lane = tid & 63, wv = tid >> 6;
  const int lr = lane & 15, kg = lane >> 4;
  const floatx4 Z4 = {0.f, 0.f, 0.f, 0.f};

  floatx4 pse[4][4];
#pragma unroll
  for (int rt = 0; rt < 4; ++rt)
#pragma unroll
    for (int j = 0; j < 4; ++j) {
      const int row = rt*16 + kg*4 + j;
      const floatx4 a = *(const floatx4*)(pes + (size_t)sidx[row] * HH + wv*64 + lr*4);
      const floatx4 b = *(const floatx4*)(pet + (size_t)tidx[row] * HH + wv*64 + lr*4);
      pse[rt][j] = a + b;
    }

  floatx4 acc[4][4];
#pragma unroll
  for (int i = 0; i < 4; ++i)
#pragma unroll
    for (int j = 0; j < 4; ++j) acc[i][j] = Z4;
#pragma unroll
  for (int sub = 0; sub < 4; ++sub) {
    const int off = sub*32 + kg*8;
    bf16x8 ah[4], al[4], bh[4], bl[4];
#pragma unroll
    for (int rt = 0; rt < 4; ++rt)
      split8(ea + (size_t)(e0 + rt*16 + lr) * DD + off, ah[rt], al[rt]);
#pragma unroll
    for (int ct = 0; ct < 4; ++ct) {
      const size_t wo = (size_t)(wv*64 + ct*16 + lr) * 384 + 256 + off;
      bh[ct] = ld_bf8(w1h + wo); bl[ct] = ld_bf8(w1l + wo);
    }
#pragma unroll
    for (int rt = 0; rt < 4; ++rt)
#pragma unroll
      for (int ct = 0; ct < 4; ++ct) acc[rt][ct] = MFMA3(ah[rt], al[rt], bh[ct], bl[ct], acc[rt][ct]);
  }
#pragma unroll
  for (int ct = 0; ct < 4; ++ct) {
    const int col = wv*64 + ct*16 + lr;
    const float bias = b1[col];
#pragma unroll
    for (int rt = 0; rt < 4; ++rt)
#pragma unroll
      for (int j = 0; j < 4; ++j) {
        const float v = fmaxf(acc[rt][ct][j] + bias + pse[rt][j][ct], 0.f);
        const unsigned short hh = f2bf(v);
        const int idx = (rt*16 + kg*4 + j) * 264 + col;
        h_hi[idx] = hh;
        h_lo[idx] = f2bf(v - bf2f(hh));
      }
  }
  __syncthreads();

  floatx4 acc2[4][2];
#pragma unroll
  for (int i = 0; i < 4; ++i) { acc2[i][0] = Z4; acc2[i][1] = Z4; }
#pragma unroll
  for (int ch = 0; ch < 8; ++ch) {
    bf16x8 ah[4], al[4], bh[2], bl[2];
#pragma unroll
    for (int rt = 0; rt < 4; ++rt) {
      const int idx = (rt*16 + lr) * 264 + ch*32 + kg*8;
      ah[rt] = ld_bf8(&h_hi[idx]); al[rt] = ld_bf8(&h_lo[idx]);
    }
#pragma unroll
    for (int c2 = 0; c2 < 2; ++c2) {
      const size_t wo = (size_t)(wv*32 + c2*16 + lr) * 256 + ch*32 + kg*8;
      bh[c2] = ld_bf8(w2h + wo); bl[c2] = ld_bf8(w2l + wo);
    }
#pragma unroll
    for (int rt = 0; rt < 4; ++rt)
#pragma unroll
      for (int c2 = 0; c2 < 2; ++c2) acc2[rt][c2] = MFMA3(ah[rt], al[rt], bh[c2], bl[c2], acc2[rt][c2]);
  }
#pragma unroll
  for (int c2 = 0; c2 < 2; ++c2) {
    const int col = wv*32 + c2*16 + lr;
    const float bias = b2[col];
#pragma unroll
    for (int rt = 0; rt < 4; ++rt)
#pragma unroll
      for (int j = 0; j < 4; ++j) {
        const float fv = acc2[rt][c2][j] + bias;
        const size_t idx = (size_t)(e0 + rt*16 + kg*4 + j) * DD + col;
        ief32[idx] = fv;
        eff32[idx] = fv;
      }
  }
}

// ---------------- fused per-iteration edge kernel (R11 base; eraw in hi/lo LDS) ----------------

__launch_bounds__(256, 2)
__global__ void edge_iter_kernel(
    const float* __restrict__ ief32,
    float* __restrict__ eff32,
    const int* __restrict__ ei,
    const float* __restrict__ pse_,
    const float* __restrict__ pte_,
    const float* __restrict__ psm_,
    const unsigned short* __restrict__ ew1h, const unsigned short* __restrict__ ew1l,
    const float* __restrict__ eb1,
    const unsigned short* __restrict__ ew2h, const unsigned short* __restrict__ ew2l,
    const float* __restrict__ eb2,
    const unsigned short* __restrict__ mw1h, const unsigned short* __restrict__ mw1l,
    const float* __restrict__ mb1,
    const unsigned short* __restrict__ mw2h, const unsigned short* __restrict__ mw2l,
    const float* __restrict__ mb2,
    const float* __restrict__ lng, const float* __restrict__ lnb,
    float* __restrict__ agg,
    float* __restrict__ out_edge,
    int write_out)
{
  __shared__ unsigned short h_hi[EB * 264];
  __shared__ unsigned short h_lo[EB * 264];
  __shared__ unsigned short eraw_hi[EB * 136];
  __shared__ unsigned short eraw_lo[EB * 136];
  __shared__ int sidx[EB];
  __shared__ int tidx[EB];

  const int tid = threadIdx.x;
  const int e0 = blockIdx.x * EB;
  if (tid < EB) {
    const int e = e0 + tid;
    const int ec = (e < NE) ? e : (NE - 1);
    sidx[tid] = ei[ec];
    tidx[tid] = ei[NE + ec];
  }
  __syncthreads();

  const int lane = tid & 63, wv = tid >> 6;
  const int lr = lane & 15, kg = lane >> 4;
  int erow_c[3];
#pragma unroll
  for (int rt = 0; rt < 3; ++rt) {
    const int er = e0 + rt*16 + lr;
    erow_c[rt] = (er < NE) ? er : (NE - 1);
  }
  const floatx4 Z4 = {0.f, 0.f, 0.f, 0.f};

  // ===== psum gathers (vectorized: one floatx4 per row) =====
  floatx4 pse[3][4];
#pragma unroll
  for (int rt = 0; rt < 3; ++rt)
#pragma unroll
    for (int j = 0; j < 4; ++j) {
      const int row = rt*16 + kg*4 + j;
      const floatx4 a = *(const floatx4*)(pse_ + (size_t)sidx[row] * HH + wv*64 + lr*4);
      const floatx4 b = *(const floatx4*)(pte_ + (size_t)tidx[row] * HH + wv*64 + lr*4);
      pse[rt][j] = a + b;
    }

  // ===== P2: edge MLP layer 1, edge_c part (K=256: ie | ef) =====
  floatx4 acc[3][4];
#pragma unroll
  for (int i = 0; i < 3; ++i)
#pragma unroll
    for (int j = 0; j < 4; ++j) acc[i][j] = Z4;

#pragma unroll
  for (int seg = 0; seg < 2; ++seg) {
    const float* fb[3];
#pragma unroll
    for (int rt = 0; rt < 3; ++rt) {
      const size_t e = (size_t)erow_c[rt] * DD;
      fb[rt] = (seg == 0) ? ief32 + e : eff32 + e;
    }
#pragma unroll
    for (int sub = 0; sub < 4; ++sub) {
      const int off = sub*32 + kg*8;
      bf16x8 ah[3], al[3], bh[4], bl[4];
#pragma unroll
      for (int rt = 0; rt < 3; ++rt) split8(fb[rt] + off, ah[rt], al[rt]);
#pragma unroll
      for (int ct = 0; ct < 4; ++ct) {
        const size_t wo = (size_t)(wv*64 + ct*16 + lr) * 768 + 512 + seg*128 + off;
        bh[ct] = ld_bf8(ew1h + wo); bl[ct] = ld_bf8(ew1l + wo);
      }
#pragma unroll
      for (int rt = 0; rt < 3; ++rt)
#pragma unroll
        for (int ct = 0; ct < 4; ++ct) acc[rt][ct] = MFMA3(ah[rt], al[rt], bh[ct], bl[ct], acc[rt][ct]);
    }
  }
#pragma unroll
  for (int ct = 0; ct < 4; ++ct) {
    const int col = wv*64 + ct*16 + lr;
    const float bias = eb1[col];
#pragma unroll
    for (int rt = 0; rt < 3; ++rt)
#pragma unroll
      for (int j = 0; j < 4; ++j) {
        const float v = fmaxf(acc[rt][ct][j] + bias + pse[rt][j][ct], 0.f);
        const unsigned short hh = f2bf(v);
        const int idx = (rt*16 + kg*4 + j) * 264 + col;
        h_hi[idx] = hh;
        h_lo[idx] = f2bf(v - bf2f(hh));
      }
  }
  __syncthreads();

  // ===== P5: edge MLP layer 2 -> eraw hi/lo LDS =====
  floatx4 acc2[3][2];
#pragma unroll
  for (int i = 0; i < 3; ++i) { acc2[i][0] = Z4; acc2[i][1] = Z4; }
#pragma unroll
  for (int ch = 0; ch < 8; ++ch) {
    bf16x8 ah[3], al[3], bh[2], bl[2];
#pragma unroll
    for (int rt = 0; rt < 3; ++rt) {
      const int idx = (rt*16 + lr) * 264 + ch*32 + kg*8;
      ah[rt] = ld_bf8(&h_hi[idx]); al[rt] = ld_bf8(&h_lo[idx]);
    }
#pragma unroll
    for (int c2 = 0; c2 < 2; ++c2) {
      const size_t wo = (size_t)(wv*32 + c2*16 + lr) * 256 + ch*32 + kg*8;
      bh[c2] = ld_bf8(ew2h + wo); bl[c2] = ld_bf8(ew2l + wo);
    }
#pragma unroll
    for (int rt = 0; rt < 3; ++rt)
#pragma unroll
      for (int c2 = 0; c2 < 2; ++c2) acc2[rt][c2] = MFMA3(ah[rt], al[rt], bh[c2], bl[c2], acc2[rt][c2]);
  }
#pragma unroll
  for (int c2 = 0; c2 < 2; ++c2) {
    const int col = wv*32 + c2*16 + lr;
    const float bias = eb2[col];
#pragma unroll
    for (int rt = 0; rt < 3; ++rt)
#pragma unroll
      for (int j = 0; j < 4; ++j) {
        const float v = acc2[rt][c2][j] + bias;
        const unsigned short hh = f2bf(v);
        const int idx = (rt*16 + kg*4 + j) * 136 + col;
        eraw_hi[idx] = hh;
        eraw_lo[idx] = f2bf(v - bf2f(hh));
      }
  }
  __syncthreads();

  // ===== P6: msg MLP layer 1, eraw part (K=128) + psrc_m seed (vectorized) =====
  floatx4 psm[3][4];
#pragma unroll
  for (int rt = 0; rt < 3; ++rt)
#pragma unroll
    for (int j = 0; j < 4; ++j) {
      const int row = rt*16 + kg*4 + j;
      psm[rt][j] = *(const floatx4*)(psm_ + (size_t)sidx[row] * HH + wv*64 + lr*4);
    }

  floatx4 accm[3][4];
#pragma unroll
  for (int i = 0; i < 3; ++i)
#pragma unroll
    for (int j = 0; j < 4; ++j) accm[i][j] = Z4;
#pragma unroll
  for (int sub = 0; sub < 4; ++sub) {
    const int off = sub*32 + kg*8;
    bf16x8 ah[3], al[3], bh[4], bl[4];
#pragma unroll
    for (int rt = 0; rt < 3; ++rt) {
      const int idx = (rt*16 + lr) * 136 + off;
      ah[rt] = ld_bf8(&eraw_hi[idx]); al[rt] = ld_bf8(&eraw_lo[idx]);
    }
#pragma unroll
    for (int ct = 0; ct < 4; ++ct) {
      const size_t wo = (size_t)(wv*64 + ct*16 + lr) * 384 + 256 + off;
      bh[ct] = ld_bf8(mw1h + wo); bl[ct] = ld_bf8(mw1l + wo);
    }
#pragma unroll
    for (int rt = 0; rt < 3; ++rt)
#pragma unroll
      for (int ct = 0; ct < 4; ++ct) accm[rt][ct] = MFMA3(ah[rt], al[rt], bh[ct], bl[ct], accm[rt][ct]);
  }
#pragma unroll
  for (int ct = 0; ct < 4; ++ct) {
    const int col = wv*64 + ct*16 + lr;
    const float bias = mb1[col];
#pragma unroll
    for (int rt = 0; rt < 3; ++rt)
#pragma unroll
      for (int j = 0; j < 4; ++j) {
        const float v = fmaxf(accm[rt][ct][j] + bias + psm[rt][j][ct], 0.f);
        const unsigned short hh = f2bf(v);
        const int idx = (rt*16 + kg*4 + j) * 264 + col;
        h_hi[idx] = hh;
        h_lo[idx] = f2bf(v - bf2f(hh));
      }
  }
  __syncthreads();

  // ===== P7: msg MLP layer 2 + atomic scatter =====
  floatx4 accq[3][2];
#pragma unroll
  for (int i = 0; i < 3; ++i) { accq[i][0] = Z4; accq[i][1] = Z4; }
#pragma unroll
  for (int ch = 0; ch < 8; ++ch) {
    bf16x8 ah[3], al[3], bh[2], bl[2];
#pragma unroll
    for (int rt = 0; rt < 3; ++rt) {
      const int idx = (rt*16 + lr) * 264 + ch*32 + kg*8;
      ah[rt] = ld_bf8(&h_hi[idx]); al[rt] = ld_bf8(&h_lo[idx]);
    }
#pragma unroll
    for (int c2 = 0; c2 < 2; ++c2) {
      const size_t wo = (size_t)(wv*32 + c2*16 + lr) * 256 + ch*32 + kg*8;
      bh[c2] = ld_bf8(mw2h + wo); bl[c2] = ld_bf8(mw2l + wo);
    }
#pragma unroll
    for (int rt = 0; rt < 3; ++rt)
#pragma unroll
      for (int c2 = 0; c2 < 2; ++c2) accq[rt][c2] = MFMA3(ah[rt], al[rt], bh[c2], bl[c2], accq[rt][c2]);
  }
#pragma unroll
  for (int c2 = 0; c2 < 2; ++c2) {
    const int col = wv*32 + c2*16 + lr;
    const float bias = mb2[col];
#pragma unroll
    for (int rt = 0; rt < 3; ++rt)
#pragma unroll
      for (int j = 0; j < 4; ++j) {
        const int row = rt*16 + kg*4 + j;
        if (e0 + row < NE)
          atomicAdd(&agg[(size_t)tidx[row] * DD + col], accq[rt][c2][j] + bias);
      }
  }

  // ===== residual + LayerNorm (f32) -> eff32 (state) and d_out (final iter) =====
  if (tid < EB * 4) {
    const int row = tid >> 2, sub = tid & 3;
    const int er = e0 + row;
    if (er < NE) {
      const size_t e = (size_t)er;
      float v[32];
      float s = 0.f, ss = 0.f;
#pragma unroll
      for (int c8 = 0; c8 < 4; ++c8) {
        const int li = row * 136 + sub*32 + c8*8;
        ushort8 rh = *(const ushort8*)&eraw_hi[li];
        ushort8 rl = *(const ushort8*)&eraw_lo[li];
        const float* ip = &ief32[e * DD + sub*32 + c8*8];
        floatx4 i0 = *(const floatx4*)ip;
        floatx4 i1 = *(const floatx4*)(ip + 4);
#pragma unroll
        for (int k = 0; k < 4; ++k) {
          float v0 = (bf2f(rh[k]) + bf2f(rl[k])) + i0[k];
          float v1 = (bf2f(rh[k+4]) + bf2f(rl[k+4])) + i1[k];
          v[c8*8 + k] = v0; v[c8*8 + 4 + k] = v1;
          s += v0 + v1; ss += v0*v0 + v1*v1;
        }
      }
      s  += __shfl_xor(s, 1);  s  += __shfl_xor(s, 2);
      ss += __shfl_xor(ss, 1); ss += __shfl_xor(ss, 2);
      const float mu  = s * (1.f/128.f);
      const float var = ss * (1.f/128.f) - mu * mu;
      const float inv = rsqrtf(fmaxf(var, 0.f) + 1e-5f);
#pragma unroll
      for (int c8 = 0; c8 < 4; ++c8) {
        floatx4 o0, o1;
#pragma unroll
        for (int k = 0; k < 8; ++k) {
          const int col = sub*32 + c8*8 + k;
          const float o = (v[c8*8 + k] - mu) * inv * lng[col] + lnb[col];
          if (k < 4) o0[k] = o; else o1[k-4] = o;
        }
        *(floatx4*)&eff32[e * DD + sub*32 + c8*8] = o0;
        *(floatx4*)&eff32[e * DD + sub*32 + c8*8 + 4] = o1;
        if (write_out) {
          *(floatx4*)&out_edge[e * DD + sub*32 + c8*8] = o0;
          *(floatx4*)&out_edge[e * DD + sub*32 + c8*8 + 4] = o1;
        }
      }
    }
  }
}

// ---------------- node update ----------------

__launch_bounds__(256, 2)
__global__ void node_update_kernel(
    const float* __restrict__ agg, const float* __restrict__ idg,
    const unsigned short* __restrict__ nwh, const unsigned short* __restrict__ nwl,
    const float* __restrict__ nb,
    const float* __restrict__ x,
    const float* __restrict__ lng, const float* __restrict__ lnb,
    float* __restrict__ out_node,
    unsigned short* __restrict__ nh, unsigned short* __restrict__ nl,
    int write_out)
{
  __shared__ unsigned short a_hi[64 * 136];
  __shared__ unsigned short a_lo[64 * 136];
  __shared__ float o_lds[64 * 132];
  const int tid = threadIdx.x;
  const int n0 = blockIdx.x * 64;
  const int row = tid >> 2, sub = tid & 3;
  const int n = n0 + row;
  {
    const float s = (n < NN) ? idg[n] : 0.f;
#pragma unroll
    for (int c4 = 0; c4 < 8; ++c4) {
      floatx4 v = {0.f, 0.f, 0.f, 0.f};
      if (n < NN) v = *(const floatx4*)&agg[(size_t)n * DD + sub*32 + c4*4];
#pragma unroll
      for (int k = 0; k < 4; ++k) {
        const float f = v[k] * s;
        const unsigned short hh = f2bf(f);
        const int idx = row * 136 + sub*32 + c4*4 + k;
        a_hi[idx] = hh;
        a_lo[idx] = f2bf(f - bf2f(hh));
      }
    }
  }
  __syncthreads();

  const int lane = tid & 63, wv = tid >> 6;
  const int lr = lane & 15, kg = lane >> 4;
  const floatx4 Z4 = {0.f, 0.f, 0.f, 0.f};
  floatx4 acc[4][2];
#pragma unroll
  for (int i = 0; i < 4; ++i) { acc[i][0] = Z4; acc[i][1] = Z4; }
#pragma unroll
  for (int ch = 0; ch < 4; ++ch) {
    bf16x8 ah[4], al[4], bh[2], bl[2];
#pragma unroll
    for (int rt = 0; rt < 4; ++rt) {
      const int idx = (rt*16 + lr) * 136 + ch*32 + kg*8;
      ah[rt] = ld_bf8(&a_hi[idx]); al[rt] = ld_bf8(&a_lo[idx]);
    }
#pragma unroll
    for (int c2 = 0; c2 < 2; ++c2) {
      const size_t wo = (size_t)(wv*32 + c2*16 + lr) * DD + ch*32 + kg*8;
      bh[c2] = ld_bf8(nwh + wo); bl[c2] = ld_bf8(nwl + wo);
    }
#pragma unroll
    for (int rt = 0; rt < 4; ++rt)
#pragma unroll
      for (int c2 = 0; c2 < 2; ++c2) acc[rt][c2] = MFMA3(ah[rt], al[rt], bh[c2], bl[c2], acc[rt][c2]);
  }
#pragma unroll
  for (int c2 = 0; c2 < 2; ++c2) {
    const int col = wv*32 + c2*16 + lr;
    const float bias = nb[col];
#pragma unroll
    for (int rt = 0; rt < 4; ++rt)
#pragma unroll
      for (int j = 0; j < 4; ++j)
        o_lds[(rt*16 + kg*4 + j) * 132 + col] = acc[rt][c2][j] + bias;
  }
  __syncthreads();

  if (n < NN) {
    float v[32];
    float s = 0.f, ss = 0.f;
#pragma unroll
    for (int c4 = 0; c4 < 8; ++c4) {
      floatx4 xa = *(const floatx4*)&x[(size_t)n * DD + sub*32 + c4*4];
#pragma unroll
      for (int k = 0; k < 4; ++k) {
        const float val = o_lds[row * 132 + sub*32 + c4*4 + k] + xa[k];
        v[c4*4 + k] = val; s += val; ss += val * val;
      }
    }
    s  += __shfl_xor(s, 1);  s  += __shfl_xor(s, 2);
    ss += __shfl_xor(ss, 1); ss += __shfl_xor(ss, 2);
    const float mu  = s * (1.f/128.f);
    const float var = ss * (1.f/128.f) - mu * mu;
    const float inv = rsqrtf(fmaxf(var, 0.f) + 1e-5f);
#pragma unroll
    for (int c8 = 0; c8 < 4; ++c8) {
      floatx4 o0, o1; ushort8 oh, ol;
#pragma unroll
      for (int k = 0; k < 8; ++k) {
        const int col = sub*32 + c8*8 + k;
        const float o = (v[c8*8 + k] - mu) * inv * lng[col] + lnb[col];
        if (k < 4) o0[k] = o; else o1[k-4] = o;
        const unsigned short hh = f2bf(o);
        oh[k] = hh;
        ol[k] = f2bf(o - bf2f(hh));
      }
      if (write_out) {
        *(floatx4*)&out_node[(size_t)n * DD + sub*32 + c8*8] = o0;
        *(floatx4*)&out_node[(size_t)n * DD + sub*32 + c8*8 + 4] = o1;
      }
      *(ushort8*)&nh[(size_t)n * DD + sub*32 + c8*8] = oh;
      *(ushort8*)&nl[(size_t)n * DD + sub*32 + c8*8] = ol;
    }
  }
}

// ---------------- host launch ----------------

extern "C" void kernel_launch(void* const* d_in, const int* in_sizes, int n_in,
                              void* d_out, int out_size, void* d_ws, size_t ws_size,
                              hipStream_t stream) {
  (void)in_sizes; (void)n_in; (void)out_size; (void)ws_size;

  const float* x      = (const float*)d_in[0];
  const float* ea     = (const float*)d_in[1];
  const int*   ei     = (const int*)d_in[2];
  const float* enc_w1 = (const float*)d_in[3];
  const float* enc_b1 = (const float*)d_in[4];
  const float* enc_w2 = (const float*)d_in[5];
  const float* enc_b2 = (const float*)d_in[6];
  const float* em_w1  = (const float*)d_in[7];
  const float* em_b1  = (const float*)d_in[8];
  const float* em_w2  = (const float*)d_in[9];
  const float* em_b2  = (const float*)d_in[10];
  const float* nm_w1  = (const float*)d_in[11];
  const float* nm_b1  = (const float*)d_in[12];
  const float* nm_w2  = (const float*)d_in[13];
  const float* nm_b2  = (const float*)d_in[14];
  const float* no_w   = (const float*)d_in[15];
  const float* no_b   = (const float*)d_in[16];
  const float* nlng   = (const float*)d_in[17];
  const float* nlnb   = (const float*)d_in[18];
  const float* elng   = (const float*)d_in[19];
  const float* elnb   = (const float*)d_in[20];

  float* out_node = (float*)d_out;
  float* ief32    = out_node + (size_t)NN * DD;  // f32 init_edge; final edge output overwrites

  char* p = (char*)d_ws;
  auto alloc = [&](size_t bytes) -> void* {
    void* r = (void*)p;
    p += (bytes + 255) & ~(size_t)255;
    return r;
  };
  unsigned short* xb_h = (unsigned short*)alloc((size_t)NN * DD * 2);
  unsigned short* xb_l = (unsigned short*)alloc((size_t)NN * DD * 2);
  unsigned short* nf_h = (unsigned short*)alloc((size_t)NN * DD * 2);
  unsigned short* nf_l = (unsigned short*)alloc((size_t)NN * DD * 2);
  float*          eff32 = (float*)alloc((size_t)NE * DD * 4);
  float*          agg  = (float*)alloc((size_t)NN * DD * 4);
  float*          deg  = (float*)alloc((size_t)NN * 4);
  float*          idg  = (float*)alloc((size_t)NN * 4);
  float*          psrc_e = (float*)alloc((size_t)NN * HH * 4);
  float*          ptgt_e = (float*)alloc((size_t)NN * HH * 4);
  float*          psrc_m = (float*)alloc((size_t)NN * HH * 4);
  unsigned short* cw1h = (unsigned short*)alloc((size_t)384 * 256 * 2);
  unsigned short* cw1l = (unsigned short*)alloc((size_t)384 * 256 * 2);
  unsigned short* cw2h = (unsigned short*)alloc((size_t)256 * 128 * 2);
  unsigned short* cw2l = (unsigned short*)alloc((size_t)256 * 128 * 2);
  unsigned short* ew1h = (unsigned short*)alloc((size_t)768 * 256 * 2);
  unsigned short* ew1l = (unsigned short*)alloc((size_t)768 * 256 * 2);
  unsigned short* ew2h = (unsigned short*)alloc((size_t)256 * 128 * 2);
  unsigned short* ew2l = (unsigned short*)alloc((size_t)256 * 128 * 2);
  unsigned short* mw1h = (unsigned short*)alloc((size_t)384 * 256 * 2);
  unsigned short* mw1l = (unsigned short*)alloc((size_t)384 * 256 * 2);
  unsigned short* mw2h = (unsigned short*)alloc((size_t)256 * 128 * 2);
  unsigned short* mw2l = (unsigned short*)alloc((size_t)256 * 128 * 2);
  unsigned short* nwh  = (unsigned short*)alloc((size_t)128 * 128 * 2);
  unsigned short* nwl  = (unsigned short*)alloc((size_t)128 * 128 * 2);

  wconv_kernel<<<(384*256 + 255)/256, 256, 0, stream>>>(enc_w1, cw1h, cw1l, 384, 256);
  wconv_kernel<<<(256*128 + 255)/256, 256, 0, stream>>>(enc_w2, cw2h, cw2l, 256, 128);
  wconv_kernel<<<(768*256 + 255)/256, 256, 0, stream>>>(em_w1, ew1h, ew1l, 768, 256);
  wconv_kernel<<<(256*128 + 255)/256, 256, 0, stream>>>(em_w2, ew2h, ew2l, 256, 128);
  wconv_kernel<<<(384*256 + 255)/256, 256, 0, stream>>>(nm_w1, mw1h, mw1l, 384, 256);
  wconv_kernel<<<(256*128 + 255)/256, 256, 0, stream>>>(nm_w2, mw2h, mw2l, 256, 128);
  wconv_kernel<<<(128*128 + 255)/256, 256, 0, stream>>>(no_w, nwh, nwl, 128, 128);

  xconv_kernel<<<(NN*DD + 255)/256, 256, 0, stream>>>(x, xb_h, xb_l, nf_h, nf_l);

  hipMemsetAsync(deg, 0, (size_t)NN * 4, stream);
  deg_kernel<<<(NE + 255)/256, 256, 0, stream>>>(ei, deg);
  inv_kernel<<<(NN + 255)/256, 256, 0, stream>>>(deg, idg);

  nodepre_kernel<4, false><<<dim3(313, 2), 256, 0, stream>>>(
      xb_h, xb_l, nf_h, nf_l,
      cw1h, cw1l, 0,   384, psrc_e,
      cw1h, cw1l, 128, 384, ptgt_e,
      cw1h, cw1l, 0,   384, psrc_e);

  encoder_kernel<<<NE/EBE, 256, 0, stream>>>(ea, ei, psrc_e, ptgt_e,
                                             cw1h, cw1l, enc_b1, cw2h, cw2l, enc_b2,
                                             ief32, eff32);

  const int egrid = (NE + EB - 1) / EB;
  for (int it = 0; it < 3; ++it) {
    const int last = (it == 2) ? 1 : 0;
    nodepre_kernel<8, true><<<dim3(313, 3), 256, 0, stream>>>(
        xb_h, xb_l, nf_h, nf_l,
        ew1h, ew1l, 0,   768, psrc_e,
        ew1h, ew1l, 256, 768, ptgt_e,
        mw1h, mw1l, 0,   384, psrc_m);
    hipMemsetAsync(agg, 0, (size_t)NN * DD * 4, stream);
    edge_iter_kernel<<<egrid, 256, 0, stream>>>(
        ief32, eff32, ei, psrc_e, ptgt_e, psrc_m,
        ew1h, ew1l, em_b1, ew2h, ew2l, em_b2,
        mw1h, mw1l, nm_b1, mw2h, mw2l, nm_b2,
        elng, elnb, agg, ief32, last);
    node_update_kernel<<<(NN + 63)/64, 256, 0, stream>>>(
        agg, idg, nwh, nwl, no_b, x, nlng, nlnb, out_node, nf_h, nf_l, last);
  }
}

// Round 14
// 3197.610 us; speedup vs baseline: 1.1662x; 1.0789x over previous
//
#include <hip/hip_runtime.h>
#include <stdint.h>

#define NN 20000
#define NE 320000
#define DD 128
#define HH 256
#define EB 64    // edges per block, edge_iter (NE/EB = 5000 exact)
#define EBE 64   // edges per block, encoder

using ushort8 = __attribute__((ext_vector_type(8))) unsigned short;
using bf16x8  = __attribute__((ext_vector_type(8))) __bf16;
using floatx4 = __attribute__((ext_vector_type(4))) float;

__device__ __forceinline__ unsigned short f2bf(float f) {
  union { float f; uint32_t u; } c; c.f = f;
  uint32_t u = c.u;
  return (unsigned short)((u + 0x7FFFu + ((u >> 16) & 1u)) >> 16);
}
__device__ __forceinline__ float bf2f(unsigned short h) {
  union { uint32_t u; float f; } c; c.u = ((uint32_t)h) << 16;
  return c.f;
}
__device__ __forceinline__ bf16x8 ld_bf8(const unsigned short* p) {
  ushort8 t = *(const ushort8*)p;
  return __builtin_bit_cast(bf16x8, t);
}
__device__ __forceinline__ void split8(const float* p, bf16x8& hi, bf16x8& lo) {
  floatx4 f0 = *(const floatx4*)p;
  floatx4 f1 = *(const floatx4*)(p + 4);
  ushort8 h, l;
#pragma unroll
  for (int k = 0; k < 4; ++k) {
    unsigned short a = f2bf(f0[k]);
    h[k] = a; l[k] = f2bf(f0[k] - bf2f(a));
    unsigned short b = f2bf(f1[k]);
    h[k+4] = b; l[k+4] = f2bf(f1[k] - bf2f(b));
  }
  hi = __builtin_bit_cast(bf16x8, h);
  lo = __builtin_bit_cast(bf16x8, l);
}
__device__ __forceinline__ floatx4 MFMA3(bf16x8 ah, bf16x8 al, bf16x8 bh, bf16x8 bl, floatx4 c) {
  c = __builtin_amdgcn_mfma_f32_16x16x32_bf16(ah, bh, c, 0, 0, 0);
  c = __builtin_amdgcn_mfma_f32_16x16x32_bf16(al, bh, c, 0, 0, 0);
  c = __builtin_amdgcn_mfma_f32_16x16x32_bf16(ah, bl, c, 0, 0, 0);
  return c;
}

// ---------------- small prep kernels ----------------

__global__ void wconv_kernel(const float* __restrict__ in,
                             unsigned short* __restrict__ out_hi,
                             unsigned short* __restrict__ out_lo,
                             int K, int Nc) {
  int i = blockIdx.x * 256 + threadIdx.x;
  if (i >= K * Nc) return;
  int k = i / Nc, n = i - k * Nc;
  float v = in[i];
  unsigned short h = f2bf(v);
  out_hi[(size_t)n * K + k] = h;
  out_lo[(size_t)n * K + k] = f2bf(v - bf2f(h));
}

__global__ void xconv_kernel(const float* __restrict__ x,
                             unsigned short* __restrict__ xh, unsigned short* __restrict__ xl,
                             unsigned short* __restrict__ nh, unsigned short* __restrict__ nl) {
  int i = blockIdx.x * 256 + threadIdx.x;
  if (i < NN * DD) {
    float v = x[i];
    unsigned short h = f2bf(v), l = f2bf(v - bf2f(h));
    xh[i] = h; xl[i] = l; nh[i] = h; nl[i] = l;
  }
}

__global__ void deg_kernel(const int* __restrict__ ei, float* __restrict__ deg) {
  int e = blockIdx.x * 256 + threadIdx.x;
  if (e < NE) atomicAdd(&deg[ei[NE + e]], 1.0f);
}

__global__ void inv_kernel(const float* __restrict__ deg, float* __restrict__ idg) {
  int n = blockIdx.x * 256 + threadIdx.x;
  if (n < NN) idg[n] = 1.0f / fmaxf(deg[n], 1.0f);
}

// ---------------- per-node partial pre-activation GEMM ----------------
// psum layout (vectorized gathers): addr = n*256 + wv*64 + lr*4 + ct, col = wv*64 + ct*16 + lr

template<int NCH, bool USE_NF>
__launch_bounds__(256, 2)
__global__ void nodepre_kernel(
    const unsigned short* __restrict__ xh, const unsigned short* __restrict__ xl,
    const unsigned short* __restrict__ nh, const unsigned short* __restrict__ nl,
    const unsigned short* __restrict__ w0h, const unsigned short* __restrict__ w0l,
    int ko0, int st0, float* __restrict__ out0,
    const unsigned short* __restrict__ w1h, const unsigned short* __restrict__ w1l,
    int ko1, int st1, float* __restrict__ out1,
    const unsigned short* __restrict__ w2h, const unsigned short* __restrict__ w2l,
    int ko2, int st2, float* __restrict__ out2)
{
  const int y = blockIdx.y;
  const unsigned short* Wh = (y == 0) ? w0h : (y == 1) ? w1h : w2h;
  const unsigned short* Wl = (y == 0) ? w0l : (y == 1) ? w1l : w2l;
  const int ko = (y == 0) ? ko0 : (y == 1) ? ko1 : ko2;
  const int st = (y == 0) ? st0 : (y == 1) ? st1 : st2;
  float* out = (y == 0) ? out0 : (y == 1) ? out1 : out2;

  const int tid = threadIdx.x;
  const int n0 = blockIdx.x * 64;
  const int lane = tid & 63, wv = tid >> 6;
  const int lr = lane & 15, kg = lane >> 4;
  int nr[4];
#pragma unroll
  for (int rt = 0; rt < 4; ++rt) {
    const int n = n0 + rt*16 + lr;
    nr[rt] = (n < NN) ? n : (NN - 1);
  }
  const floatx4 Z4 = {0.f, 0.f, 0.f, 0.f};
  floatx4 acc[4][4];
#pragma unroll
  for (int i = 0; i < 4; ++i)
#pragma unroll
    for (int j = 0; j < 4; ++j) acc[i][j] = Z4;

#pragma unroll
  for (int ch = 0; ch < NCH; ++ch) {
    bf16x8 ah[4], al[4], bh[4], bl[4];
#pragma unroll
    for (int rt = 0; rt < 4; ++rt) {
      if (USE_NF && ch >= 4) {
        const size_t off = (size_t)nr[rt] * DD + (ch - 4)*32 + kg*8;
        ah[rt] = ld_bf8(nh + off); al[rt] = ld_bf8(nl + off);
      } else {
        const size_t off = (size_t)nr[rt] * DD + ch*32 + kg*8;
        ah[rt] = ld_bf8(xh + off); al[rt] = ld_bf8(xl + off);
      }
    }
#pragma unroll
    for (int ct = 0; ct < 4; ++ct) {
      const size_t wo = (size_t)(wv*64 + ct*16 + lr) * st + ko + ch*32 + kg*8;
      bh[ct] = ld_bf8(Wh + wo); bl[ct] = ld_bf8(Wl + wo);
    }
#pragma unroll
    for (int rt = 0; rt < 4; ++rt)
#pragma unroll
      for (int ct = 0; ct < 4; ++ct) acc[rt][ct] = MFMA3(ah[rt], al[rt], bh[ct], bl[ct], acc[rt][ct]);
  }
#pragma unroll
  for (int ct = 0; ct < 4; ++ct) {
#pragma unroll
    for (int rt = 0; rt < 4; ++rt)
#pragma unroll
      for (int j = 0; j < 4; ++j) {
        const int n = n0 + rt*16 + kg*4 + j;
        if (n < NN) out[(size_t)n * HH + wv*64 + lr*4 + ct] = acc[rt][ct][j];
      }
  }
}

// ---------------- edge encoder (psum-seeded, vectorized gathers) ----------------

__launch_bounds__(256, 2)
__global__ void encoder_kernel(
    const float* __restrict__ ea,
    const int* __restrict__ ei,
    const float* __restrict__ pes,
    const float* __restrict__ pet,
    const unsigned short* __restrict__ w1h, const unsigned short* __restrict__ w1l,
    const float* __restrict__ b1,
    const unsigned short* __restrict__ w2h, const unsigned short* __restrict__ w2l,
    const float* __restrict__ b2,
    float* __restrict__ ief32, float* __restrict__ eff32)
{
  __shared__ unsigned short h_hi[EBE * 264];
  __shared__ unsigned short h_lo[EBE * 264];
  __shared__ int sidx[EBE];
  __shared__ int tidx[EBE];
  const int tid = threadIdx.x;
  const int e0 = blockIdx.x * EBE;
  if (tid < EBE) { sidx[tid] = ei[e0 + tid]; tidx[tid] = ei[NE + e0 + tid]; }
  __syncthreads();

  const int lane = tid & 63, wv = tid >> 6;
  const int lr = lane & 15, kg = lane >> 4;
  const floatx4 Z4 = {0.f, 0.f, 0.f, 0.f};

  floatx4 pse[4][4];
#pragma unroll
  for (int rt = 0; rt < 4; ++rt)
#pragma unroll
    for (int j = 0; j < 4; ++j) {
      const int row = rt*16 + kg*4 + j;
      const floatx4 a = *(const floatx4*)(pes + (size_t)sidx[row] * HH + wv*64 + lr*4);
      const floatx4 b = *(const floatx4*)(pet + (size_t)tidx[row] * HH + wv*64 + lr*4);
      pse[rt][j] = a + b;
    }

  floatx4 acc[4][4];
#pragma unroll
  for (int i = 0; i < 4; ++i)
#pragma unroll
    for (int j = 0; j < 4; ++j) acc[i][j] = Z4;
#pragma unroll
  for (int sub = 0; sub < 4; ++sub) {
    const int off = sub*32 + kg*8;
    bf16x8 ah[4], al[4], bh[4], bl[4];
#pragma unroll
    for (int rt = 0; rt < 4; ++rt)
      split8(ea + (size_t)(e0 + rt*16 + lr) * DD + off, ah[rt], al[rt]);
#pragma unroll
    for (int ct = 0; ct < 4; ++ct) {
      const size_t wo = (size_t)(wv*64 + ct*16 + lr) * 384 + 256 + off;
      bh[ct] = ld_bf8(w1h + wo); bl[ct] = ld_bf8(w1l + wo);
    }
#pragma unroll
    for (int rt = 0; rt < 4; ++rt)
#pragma unroll
      for (int ct = 0; ct < 4; ++ct) acc[rt][ct] = MFMA3(ah[rt], al[rt], bh[ct], bl[ct], acc[rt][ct]);
  }
#pragma unroll
  for (int ct = 0; ct < 4; ++ct) {
    const int col = wv*64 + ct*16 + lr;
    const float bias = b1[col];
#pragma unroll
    for (int rt = 0; rt < 4; ++rt)
#pragma unroll
      for (int j = 0; j < 4; ++j) {
        const float v = fmaxf(acc[rt][ct][j] + bias + pse[rt][j][ct], 0.f);
        const unsigned short hh = f2bf(v);
        const int idx = (rt*16 + kg*4 + j) * 264 + col;
        h_hi[idx] = hh;
        h_lo[idx] = f2bf(v - bf2f(hh));
      }
  }
  __syncthreads();

  floatx4 acc2[4][2];
#pragma unroll
  for (int i = 0; i < 4; ++i) { acc2[i][0] = Z4; acc2[i][1] = Z4; }
#pragma unroll
  for (int ch = 0; ch < 8; ++ch) {
    bf16x8 ah[4], al[4], bh[2], bl[2];
#pragma unroll
    for (int rt = 0; rt < 4; ++rt) {
      const int idx = (rt*16 + lr) * 264 + ch*32 + kg*8;
      ah[rt] = ld_bf8(&h_hi[idx]); al[rt] = ld_bf8(&h_lo[idx]);
    }
#pragma unroll
    for (int c2 = 0; c2 < 2; ++c2) {
      const size_t wo = (size_t)(wv*32 + c2*16 + lr) * 256 + ch*32 + kg*8;
      bh[c2] = ld_bf8(w2h + wo); bl[c2] = ld_bf8(w2l + wo);
    }
#pragma unroll
    for (int rt = 0; rt < 4; ++rt)
#pragma unroll
      for (int c2 = 0; c2 < 2; ++c2) acc2[rt][c2] = MFMA3(ah[rt], al[rt], bh[c2], bl[c2], acc2[rt][c2]);
  }
#pragma unroll
  for (int c2 = 0; c2 < 2; ++c2) {
    const int col = wv*32 + c2*16 + lr;
    const float bias = b2[col];
#pragma unroll
    for (int rt = 0; rt < 4; ++rt)
#pragma unroll
      for (int j = 0; j < 4; ++j) {
        const float fv = acc2[rt][c2][j] + bias;
        const size_t idx = (size_t)(e0 + rt*16 + kg*4 + j) * DD + col;
        ief32[idx] = fv;
        eff32[idx] = fv;
      }
  }
}

// ---------------- fused per-iteration edge kernel ----------------
// EB=64 (rt=4), single time-shared hi/lo LDS buffer (h_edge -> eraw -> h_msg),
// 68 KB LDS -> 2 blocks/CU, no tail (NE/64 exact).

__launch_bounds__(256, 2)
__global__ void edge_iter_kernel(
    const float* __restrict__ ief32,
    float* __restrict__ eff32,
    const int* __restrict__ ei,
    const float* __restrict__ pse_,
    const float* __restrict__ pte_,
    const float* __restrict__ psm_,
    const unsigned short* __restrict__ ew1h, const unsigned short* __restrict__ ew1l,
    const float* __restrict__ eb1,
    const unsigned short* __restrict__ ew2h, const unsigned short* __restrict__ ew2l,
    const float* __restrict__ eb2,
    const unsigned short* __restrict__ mw1h, const unsigned short* __restrict__ mw1l,
    const float* __restrict__ mb1,
    const unsigned short* __restrict__ mw2h, const unsigned short* __restrict__ mw2l,
    const float* __restrict__ mb2,
    const float* __restrict__ lng, const float* __restrict__ lnb,
    float* __restrict__ agg,
    float* __restrict__ out_edge,
    int write_out)
{
  __shared__ unsigned short bufh[EB * 264];
  __shared__ unsigned short bufl[EB * 264];
  __shared__ int sidx[EB];
  __shared__ int tidx[EB];

  const int tid = threadIdx.x;
  const int e0 = blockIdx.x * EB;
  if (tid < EB) {
    sidx[tid] = ei[e0 + tid];
    tidx[tid] = ei[NE + e0 + tid];
  }
  __syncthreads();

  const int lane = tid & 63, wv = tid >> 6;
  const int lr = lane & 15, kg = lane >> 4;
  const floatx4 Z4 = {0.f, 0.f, 0.f, 0.f};

  // ===== psum gathers (edge-MLP seed, vectorized) =====
  floatx4 pse[4][4];
#pragma unroll
  for (int rt = 0; rt < 4; ++rt)
#pragma unroll
    for (int j = 0; j < 4; ++j) {
      const int row = rt*16 + kg*4 + j;
      const floatx4 a = *(const floatx4*)(pse_ + (size_t)sidx[row] * HH + wv*64 + lr*4);
      const floatx4 b = *(const floatx4*)(pte_ + (size_t)tidx[row] * HH + wv*64 + lr*4);
      pse[rt][j] = a + b;
    }

  // ===== P2: edge MLP layer 1, edge_c part (K=256: ie | ef) =====
  floatx4 acc[4][4];
#pragma unroll
  for (int i = 0; i < 4; ++i)
#pragma unroll
    for (int j = 0; j < 4; ++j) acc[i][j] = Z4;

#pragma unroll
  for (int seg = 0; seg < 2; ++seg) {
    const float* fb[4];
#pragma unroll
    for (int rt = 0; rt < 4; ++rt) {
      const size_t e = (size_t)(e0 + rt*16 + lr) * DD;
      fb[rt] = (seg == 0) ? ief32 + e : eff32 + e;
    }
#pragma unroll
    for (int sub = 0; sub < 4; ++sub) {
      const int off = sub*32 + kg*8;
      bf16x8 ah[4], al[4], bh[4], bl[4];
#pragma unroll
      for (int rt = 0; rt < 4; ++rt) split8(fb[rt] + off, ah[rt], al[rt]);
#pragma unroll
      for (int ct = 0; ct < 4; ++ct) {
        const size_t wo = (size_t)(wv*64 + ct*16 + lr) * 768 + 512 + seg*128 + off;
        bh[ct] = ld_bf8(ew1h + wo); bl[ct] = ld_bf8(ew1l + wo);
      }
#pragma unroll
      for (int rt = 0; rt < 4; ++rt)
#pragma unroll
        for (int ct = 0; ct < 4; ++ct) acc[rt][ct] = MFMA3(ah[rt], al[rt], bh[ct], bl[ct], acc[rt][ct]);
    }
  }
  // h_edge write (stride 264)
#pragma unroll
  for (int ct = 0; ct < 4; ++ct) {
    const int col = wv*64 + ct*16 + lr;
    const float bias = eb1[col];
#pragma unroll
    for (int rt = 0; rt < 4; ++rt)
#pragma unroll
      for (int j = 0; j < 4; ++j) {
        const float v = fmaxf(acc[rt][ct][j] + bias + pse[rt][j][ct], 0.f);
        const unsigned short hh = f2bf(v);
        const int idx = (rt*16 + kg*4 + j) * 264 + col;
        bufh[idx] = hh;
        bufl[idx] = f2bf(v - bf2f(hh));
      }
  }
  __syncthreads();   // h_edge visible

  // ===== P5: edge MLP layer 2 (reads h_edge) -> acc2 registers =====
  floatx4 acc2[4][2];
#pragma unroll
  for (int i = 0; i < 4; ++i) { acc2[i][0] = Z4; acc2[i][1] = Z4; }
#pragma unroll
  for (int ch = 0; ch < 8; ++ch) {
    bf16x8 ah[4], al[4], bh[2], bl[2];
#pragma unroll
    for (int rt = 0; rt < 4; ++rt) {
      const int idx = (rt*16 + lr) * 264 + ch*32 + kg*8;
      ah[rt] = ld_bf8(&bufh[idx]); al[rt] = ld_bf8(&bufl[idx]);
    }
#pragma unroll
    for (int c2 = 0; c2 < 2; ++c2) {
      const size_t wo = (size_t)(wv*32 + c2*16 + lr) * 256 + ch*32 + kg*8;
      bh[c2] = ld_bf8(ew2h + wo); bl[c2] = ld_bf8(ew2l + wo);
    }
#pragma unroll
    for (int rt = 0; rt < 4; ++rt)
#pragma unroll
      for (int c2 = 0; c2 < 2; ++c2) acc2[rt][c2] = MFMA3(ah[rt], al[rt], bh[c2], bl[c2], acc2[rt][c2]);
  }
  __syncthreads();   // all h_edge reads done; buffer free

  // eraw write (stride 136)
#pragma unroll
  for (int c2 = 0; c2 < 2; ++c2) {
    const int col = wv*32 + c2*16 + lr;
    const float bias = eb2[col];
#pragma unroll
    for (int rt = 0; rt < 4; ++rt)
#pragma unroll
      for (int j = 0; j < 4; ++j) {
        const float v = acc2[rt][c2][j] + bias;
        const unsigned short hh = f2bf(v);
        const int idx = (rt*16 + kg*4 + j) * 136 + col;
        bufh[idx] = hh;
        bufl[idx] = f2bf(v - bf2f(hh));
      }
  }
  __syncthreads();   // eraw visible

  // ===== P6: msg MLP layer 1, eraw part (K=128) + psrc_m seed (vectorized) =====
  floatx4 psm[4][4];
#pragma unroll
  for (int rt = 0; rt < 4; ++rt)
#pragma unroll
    for (int j = 0; j < 4; ++j) {
      const int row = rt*16 + kg*4 + j;
      psm[rt][j] = *(const floatx4*)(psm_ + (size_t)sidx[row] * HH + wv*64 + lr*4);
    }

  floatx4 accm[4][4];
#pragma unroll
  for (int i = 0; i < 4; ++i)
#pragma unroll
    for (int j = 0; j < 4; ++j) accm[i][j] = Z4;
#pragma unroll
  for (int sub = 0; sub < 4; ++sub) {
    const int off = sub*32 + kg*8;
    bf16x8 ah[4], al[4], bh[4], bl[4];
#pragma unroll
    for (int rt = 0; rt < 4; ++rt) {
      const int idx = (rt*16 + lr) * 136 + off;
      ah[rt] = ld_bf8(&bufh[idx]); al[rt] = ld_bf8(&bufl[idx]);
    }
#pragma unroll
    for (int ct = 0; ct < 4; ++ct) {
      const size_t wo = (size_t)(wv*64 + ct*16 + lr) * 384 + 256 + off;
      bh[ct] = ld_bf8(mw1h + wo); bl[ct] = ld_bf8(mw1l + wo);
    }
#pragma unroll
    for (int rt = 0; rt < 4; ++rt)
#pragma unroll
      for (int ct = 0; ct < 4; ++ct) accm[rt][ct] = MFMA3(ah[rt], al[rt], bh[ct], bl[ct], accm[rt][ct]);
  }

  // ===== residual + LayerNorm (reads eraw from LDS + ief32) -> eff32 (+ d_out) =====
  {
    const int row = tid >> 2, sub = tid & 3;   // 64 rows x 4 lanes, 32 cols each
    const size_t e = (size_t)(e0 + row);
    float v[32];
    float s = 0.f, ss = 0.f;
#pragma unroll
    for (int c8 = 0; c8 < 4; ++c8) {
      const int li = row * 136 + sub*32 + c8*8;
      ushort8 rh = *(const ushort8*)&bufh[li];
      ushort8 rl = *(const ushort8*)&bufl[li];
      const float* ip = &ief32[e * DD + sub*32 + c8*8];
      floatx4 i0 = *(const floatx4*)ip;
      floatx4 i1 = *(const floatx4*)(ip + 4);
#pragma unroll
      for (int k = 0; k < 4; ++k) {
        float v0 = (bf2f(rh[k]) + bf2f(rl[k])) + i0[k];
        float v1 = (bf2f(rh[k+4]) + bf2f(rl[k+4])) + i1[k];
        v[c8*8 + k] = v0; v[c8*8 + 4 + k] = v1;
        s += v0 + v1; ss += v0*v0 + v1*v1;
      }
    }
    s  += __shfl_xor(s, 1);  s  += __shfl_xor(s, 2);
    ss += __shfl_xor(ss, 1); ss += __shfl_xor(ss, 2);
    const float mu  = s * (1.f/128.f);
    const float var = ss * (1.f/128.f) - mu * mu;
    const float inv = rsqrtf(fmaxf(var, 0.f) + 1e-5f);
#pragma unroll
    for (int c8 = 0; c8 < 4; ++c8) {
      floatx4 o0, o1;
#pragma unroll
      for (int k = 0; k < 8; ++k) {
        const int col = sub*32 + c8*8 + k;
        const float o = (v[c8*8 + k] - mu) * inv * lng[col] + lnb[col];
        if (k < 4) o0[k] = o; else o1[k-4] = o;
      }
      *(floatx4*)&eff32[e * DD + sub*32 + c8*8] = o0;
      *(floatx4*)&eff32[e * DD + sub*32 + c8*8 + 4] = o1;
      if (write_out) {
        *(floatx4*)&out_edge[e * DD + sub*32 + c8*8] = o0;
        *(floatx4*)&out_edge[e * DD + sub*32 + c8*8 + 4] = o1;
      }
    }
  }
  __syncthreads();   // all eraw reads (P6 + LN) done; buffer free

  // h_msg write (stride 264)
#pragma unroll
  for (int ct = 0; ct < 4; ++ct) {
    const int col = wv*64 + ct*16 + lr;
    const float bias = mb1[col];
#pragma unroll
    for (int rt = 0; rt < 4; ++rt)
#pragma unroll
      for (int j = 0; j < 4; ++j) {
        const float v = fmaxf(accm[rt][ct][j] + bias + psm[rt][j][ct], 0.f);
        const unsigned short hh = f2bf(v);
        const int idx = (rt*16 + kg*4 + j) * 264 + col;
        bufh[idx] = hh;
        bufl[idx] = f2bf(v - bf2f(hh));
      }
  }
  __syncthreads();   // h_msg visible

  // ===== P7: msg MLP layer 2 + atomic scatter =====
  floatx4 accq[4][2];
#pragma unroll
  for (int i = 0; i < 4; ++i) { accq[i][0] = Z4; accq[i][1] = Z4; }
#pragma unroll
  for (int ch = 0; ch < 8; ++ch) {
    bf16x8 ah[4], al[4], bh[2], bl[2];
#pragma unroll
    for (int rt = 0; rt < 4; ++rt) {
      const int idx = (rt*16 + lr) * 264 + ch*32 + kg*8;
      ah[rt] = ld_bf8(&bufh[idx]); al[rt] = ld_bf8(&bufl[idx]);
    }
#pragma unroll
    for (int c2 = 0; c2 < 2; ++c2) {
      const size_t wo = (size_t)(wv*32 + c2*16 + lr) * 256 + ch*32 + kg*8;
      bh[c2] = ld_bf8(mw2h + wo); bl[c2] = ld_bf8(mw2l + wo);
    }
#pragma unroll
    for (int rt = 0; rt < 4; ++rt)
#pragma unroll
      for (int c2 = 0; c2 < 2; ++c2) accq[rt][c2] = MFMA3(ah[rt], al[rt], bh[c2], bl[c2], accq[rt][c2]);
  }
#pragma unroll
  for (int c2 = 0; c2 < 2; ++c2) {
    const int col = wv*32 + c2*16 + lr;
    const float bias = mb2[col];
#pragma unroll
    for (int rt = 0; rt < 4; ++rt)
#pragma unroll
      for (int j = 0; j < 4; ++j) {
        const int row = rt*16 + kg*4 + j;
        atomicAdd(&agg[(size_t)tidx[row] * DD + col], accq[rt][c2][j] + bias);
      }
  }
}

// ---------------- node update ----------------

__launch_bounds__(256, 2)
__global__ void node_update_kernel(
    const float* __restrict__ agg, const float* __restrict__ idg,
    const unsigned short* __restrict__ nwh, const unsigned short* __restrict__ nwl,
    const float* __restrict__ nb,
    const float* __restrict__ x,
    const float* __restrict__ lng, const float* __restrict__ lnb,
    float* __restrict__ out_node,
    unsigned short* __restrict__ nh, unsigned short* __restrict__ nl,
    int write_out)
{
  __shared__ unsigned short a_hi[64 * 136];
  __shared__ unsigned short a_lo[64 * 136];
  __shared__ float o_lds[64 * 132];
  const int tid = threadIdx.x;
  const int n0 = blockIdx.x * 64;
  const int row = tid >> 2, sub = tid & 3;
  const int n = n0 + row;
  {
    const float s = (n < NN) ? idg[n] : 0.f;
#pragma unroll
    for (int c4 = 0; c4 < 8; ++c4) {
      floatx4 v = {0.f, 0.f, 0.f, 0.f};
      if (n < NN) v = *(const floatx4*)&agg[(size_t)n * DD + sub*32 + c4*4];
#pragma unroll
      for (int k = 0; k < 4; ++k) {
        const float f = v[k] * s;
        const unsigned short hh = f2bf(f);
        const int idx = row * 136 + sub*32 + c4*4 + k;
        a_hi[idx] = hh;
        a_lo[idx] = f2bf(f - bf2f(hh));
      }
    }
  }
  __syncthreads();

  const int lane = tid & 63, wv = tid >> 6;
  const int lr = lane & 15, kg = lane >> 4;
  const floatx4 Z4 = {0.f, 0.f, 0.f, 0.f};
  floatx4 acc[4][2];
#pragma unroll
  for (int i = 0; i < 4; ++i) { acc[i][0] = Z4; acc[i][1] = Z4; }
#pragma unroll
  for (int ch = 0; ch < 4; ++ch) {
    bf16x8 ah[4], al[4], bh[2], bl[2];
#pragma unroll
    for (int rt = 0; rt < 4; ++rt) {
      const int idx = (rt*16 + lr) * 136 + ch*32 + kg*8;
      ah[rt] = ld_bf8(&a_hi[idx]); al[rt] = ld_bf8(&a_lo[idx]);
    }
#pragma unroll
    for (int c2 = 0; c2 < 2; ++c2) {
      const size_t wo = (size_t)(wv*32 + c2*16 + lr) * DD + ch*32 + kg*8;
      bh[c2] = ld_bf8(nwh + wo); bl[c2] = ld_bf8(nwl + wo);
    }
#pragma unroll
    for (int rt = 0; rt < 4; ++rt)
#pragma unroll
      for (int c2 = 0; c2 < 2; ++c2) acc[rt][c2] = MFMA3(ah[rt], al[rt], bh[c2], bl[c2], acc[rt][c2]);
  }
#pragma unroll
  for (int c2 = 0; c2 < 2; ++c2) {
    const int col = wv*32 + c2*16 + lr;
    const float bias = nb[col];
#pragma unroll
    for (int rt = 0; rt < 4; ++rt)
#pragma unroll
      for (int j = 0; j < 4; ++j)
        o_lds[(rt*16 + kg*4 + j) * 132 + col] = acc[rt][c2][j] + bias;
  }
  __syncthreads();

  if (n < NN) {
    float v[32];
    float s = 0.f, ss = 0.f;
#pragma unroll
    for (int c4 = 0; c4 < 8; ++c4) {
      floatx4 xa = *(const floatx4*)&x[(size_t)n * DD + sub*32 + c4*4];
#pragma unroll
      for (int k = 0; k < 4; ++k) {
        const float val = o_lds[row * 132 + sub*32 + c4*4 + k] + xa[k];
        v[c4*4 + k] = val; s += val; ss += val * val;
      }
    }
    s  += __shfl_xor(s, 1);  s  += __shfl_xor(s, 2);
    ss += __shfl_xor(ss, 1); ss += __shfl_xor(ss, 2);
    const float mu  = s * (1.f/128.f);
    const float var = ss * (1.f/128.f) - mu * mu;
    const float inv = rsqrtf(fmaxf(var, 0.f) + 1e-5f);
#pragma unroll
    for (int c8 = 0; c8 < 4; ++c8) {
      floatx4 o0, o1; ushort8 oh, ol;
#pragma unroll
      for (int k = 0; k < 8; ++k) {
        const int col = sub*32 + c8*8 + k;
        const float o = (v[c8*8 + k] - mu) * inv * lng[col] + lnb[col];
        if (k < 4) o0[k] = o; else o1[k-4] = o;
        const unsigned short hh = f2bf(o);
        oh[k] = hh;
        ol[k] = f2bf(o - bf2f(hh));
      }
      if (write_out) {
        *(floatx4*)&out_node[(size_t)n * DD + sub*32 + c8*8] = o0;
        *(floatx4*)&out_node[(size_t)n * DD + sub*32 + c8*8 + 4] = o1;
      }
      *(ushort8*)&nh[(size_t)n * DD + sub*32 + c8*8] = oh;
      *(ushort8*)&nl[(size_t)n * DD + sub*32 + c8*8] = ol;
    }
  }
}

// ---------------- host launch ----------------

extern "C" void kernel_launch(void* const* d_in, const int* in_sizes, int n_in,
                              void* d_out, int out_size, void* d_ws, size_t ws_size,
                              hipStream_t stream) {
  (void)in_sizes; (void)n_in; (void)out_size; (void)ws_size;

  const float* x      = (const float*)d_in[0];
  const float* ea     = (const float*)d_in[1];
  const int*   ei     = (const int*)d_in[2];
  const float* enc_w1 = (const float*)d_in[3];
  const float* enc_b1 = (const float*)d_in[4];
  const float* enc_w2 = (const float*)d_in[5];
  const float* enc_b2 = (const float*)d_in[6];
  const float* em_w1  = (const float*)d_in[7];
  const float* em_b1  = (const float*)d_in[8];
  const float* em_w2  = (const float*)d_in[9];
  const float* em_b2  = (const float*)d_in[10];
  const float* nm_w1  = (const float*)d_in[11];
  const float* nm_b1  = (const float*)d_in[12];
  const float* nm_w2  = (const float*)d_in[13];
  const float* nm_b2  = (const float*)d_in[14];
  const float* no_w   = (const float*)d_in[15];
  const float* no_b   = (const float*)d_in[16];
  const float* nlng   = (const float*)d_in[17];
  const float* nlnb   = (const float*)d_in[18];
  const float* elng   = (const float*)d_in[19];
  const float* elnb   = (const float*)d_in[20];

  float* out_node = (float*)d_out;
  float* ief32    = out_node + (size_t)NN * DD;  // f32 init_edge; final edge output overwrites

  char* p = (char*)d_ws;
  auto alloc = [&](size_t bytes) -> void* {
    void* r = (void*)p;
    p += (bytes + 255) & ~(size_t)255;
    return r;
  };
  unsigned short* xb_h = (unsigned short*)alloc((size_t)NN * DD * 2);
  unsigned short* xb_l = (unsigned short*)alloc((size_t)NN * DD * 2);
  unsigned short* nf_h = (unsigned short*)alloc((size_t)NN * DD * 2);
  unsigned short* nf_l = (unsigned short*)alloc((size_t)NN * DD * 2);
  float*          eff32 = (float*)alloc((size_t)NE * DD * 4);
  float*          agg  = (float*)alloc((size_t)NN * DD * 4);
  float*          deg  = (float*)alloc((size_t)NN * 4);
  float*          idg  = (float*)alloc((size_t)NN * 4);
  float*          psrc_e = (float*)alloc((size_t)NN * HH * 4);
  float*          ptgt_e = (float*)alloc((size_t)NN * HH * 4);
  float*          psrc_m = (float*)alloc((size_t)NN * HH * 4);
  unsigned short* cw1h = (unsigned short*)alloc((size_t)384 * 256 * 2);
  unsigned short* cw1l = (unsigned short*)alloc((size_t)384 * 256 * 2);
  unsigned short* cw2h = (unsigned short*)alloc((size_t)256 * 128 * 2);
  unsigned short* cw2l = (unsigned short*)alloc((size_t)256 * 128 * 2);
  unsigned short* ew1h = (unsigned short*)alloc((size_t)768 * 256 * 2);
  unsigned short* ew1l = (unsigned short*)alloc((size_t)768 * 256 * 2);
  unsigned short* ew2h = (unsigned short*)alloc((size_t)256 * 128 * 2);
  unsigned short* ew2l = (unsigned short*)alloc((size_t)256 * 128 * 2);
  unsigned short* mw1h = (unsigned short*)alloc((size_t)384 * 256 * 2);
  unsigned short* mw1l = (unsigned short*)alloc((size_t)384 * 256 * 2);
  unsigned short* mw2h = (unsigned short*)alloc((size_t)256 * 128 * 2);
  unsigned short* mw2l = (unsigned short*)alloc((size_t)256 * 128 * 2);
  unsigned short* nwh  = (unsigned short*)alloc((size_t)128 * 128 * 2);
  unsigned short* nwl  = (unsigned short*)alloc((size_t)128 * 128 * 2);

  wconv_kernel<<<(384*256 + 255)/256, 256, 0, stream>>>(enc_w1, cw1h, cw1l, 384, 256);
  wconv_kernel<<<(256*128 + 255)/256, 256, 0, stream>>>(enc_w2, cw2h, cw2l, 256, 128);
  wconv_kernel<<<(768*256 + 255)/256, 256, 0, stream>>>(em_w1, ew1h, ew1l, 768, 256);
  wconv_kernel<<<(256*128 + 255)/256, 256, 0, stream>>>(em_w2, ew2h, ew2l, 256, 128);
  wconv_kernel<<<(384*256 + 255)/256, 256, 0, stream>>>(nm_w1, mw1h, mw1l, 384, 256);
  wconv_kernel<<<(256*128 + 255)/256, 256, 0, stream>>>(nm_w2, mw2h, mw2l, 256, 128);
  wconv_kernel<<<(128*128 + 255)/256, 256, 0, stream>>>(no_w, nwh, nwl, 128, 128);

  xconv_kernel<<<(NN*DD + 255)/256, 256, 0, stream>>>(x, xb_h, xb_l, nf_h, nf_l);

  hipMemsetAsync(deg, 0, (size_t)NN * 4, stream);
  deg_kernel<<<(NE + 255)/256, 256, 0, stream>>>(ei, deg);
  inv_kernel<<<(NN + 255)/256, 256, 0, stream>>>(deg, idg);

  nodepre_kernel<4, false><<<dim3(313, 2), 256, 0, stream>>>(
      xb_h, xb_l, nf_h, nf_l,
      cw1h, cw1l, 0,   384, psrc_e,
      cw1h, cw1l, 128, 384, ptgt_e,
      cw1h, cw1l, 0,   384, psrc_e);

  encoder_kernel<<<NE/EBE, 256, 0, stream>>>(ea, ei, psrc_e, ptgt_e,
                                             cw1h, cw1l, enc_b1, cw2h, cw2l, enc_b2,
                                             ief32, eff32);

  const int egrid = NE / EB;   // 5000 exact
  for (int it = 0; it < 3; ++it) {
    const int last = (it == 2) ? 1 : 0;
    nodepre_kernel<8, true><<<dim3(313, 3), 256, 0, stream>>>(
        xb_h, xb_l, nf_h, nf_l,
        ew1h, ew1l, 0,   768, psrc_e,
        ew1h, ew1l, 256, 768, ptgt_e,
        mw1h, mw1l, 0,   384, psrc_m);
    hipMemsetAsync(agg, 0, (size_t)NN * DD * 4, stream);
    edge_iter_kernel<<<egrid, 256, 0, stream>>>(
        ief32, eff32, ei, psrc_e, ptgt_e, psrc_m,
        ew1h, ew1l, em_b1, ew2h, ew2l, em_b2,
        mw1h, mw1l, nm_b1, mw2h, mw2l, nm_b2,
        elng, elnb, agg, ief32, last);
    node_update_kernel<<<(NN + 63)/64, 256, 0, stream>>>(
        agg, idg, nwh, nwl, no_b, x, nlng, nlnb, out_node, nf_h, nf_l, last);
  }
}

// Round 15
// 3125.314 us; speedup vs baseline: 1.1932x; 1.0231x over previous
//
#include <hip/hip_runtime.h>
#include <stdint.h>

#define NN 20000
#define NE 320000
#define DD 128
#define HH 256
#define EB 64    // edges per block, edge_iter (NE/EB = 5000 exact)
#define EBE 64   // edges per block, encoder

using ushort8 = __attribute__((ext_vector_type(8))) unsigned short;
using bf16x8  = __attribute__((ext_vector_type(8))) __bf16;
using floatx4 = __attribute__((ext_vector_type(4))) float;

__device__ __forceinline__ unsigned short f2bf(float f) {
  union { float f; uint32_t u; } c; c.f = f;
  uint32_t u = c.u;
  return (unsigned short)((u + 0x7FFFu + ((u >> 16) & 1u)) >> 16);
}
__device__ __forceinline__ float bf2f(unsigned short h) {
  union { uint32_t u; float f; } c; c.u = ((uint32_t)h) << 16;
  return c.f;
}
__device__ __forceinline__ bf16x8 ld_bf8(const unsigned short* p) {
  ushort8 t = *(const ushort8*)p;
  return __builtin_bit_cast(bf16x8, t);
}
__device__ __forceinline__ void split8(const float* p, bf16x8& hi, bf16x8& lo) {
  floatx4 f0 = *(const floatx4*)p;
  floatx4 f1 = *(const floatx4*)(p + 4);
  ushort8 h, l;
#pragma unroll
  for (int k = 0; k < 4; ++k) {
    unsigned short a = f2bf(f0[k]);
    h[k] = a; l[k] = f2bf(f0[k] - bf2f(a));
    unsigned short b = f2bf(f1[k]);
    h[k+4] = b; l[k+4] = f2bf(f1[k] - bf2f(b));
  }
  hi = __builtin_bit_cast(bf16x8, h);
  lo = __builtin_bit_cast(bf16x8, l);
}
__device__ __forceinline__ floatx4 MFMA3(bf16x8 ah, bf16x8 al, bf16x8 bh, bf16x8 bl, floatx4 c) {
  c = __builtin_amdgcn_mfma_f32_16x16x32_bf16(ah, bh, c, 0, 0, 0);
  c = __builtin_amdgcn_mfma_f32_16x16x32_bf16(al, bh, c, 0, 0, 0);
  c = __builtin_amdgcn_mfma_f32_16x16x32_bf16(ah, bl, c, 0, 0, 0);
  return c;
}

// ---------------- small prep kernels ----------------

__global__ void wconv_kernel(const float* __restrict__ in,
                             unsigned short* __restrict__ out_hi,
                             unsigned short* __restrict__ out_lo,
                             int K, int Nc) {
  int i = blockIdx.x * 256 + threadIdx.x;
  if (i >= K * Nc) return;
  int k = i / Nc, n = i - k * Nc;
  float v = in[i];
  unsigned short h = f2bf(v);
  out_hi[(size_t)n * K + k] = h;
  out_lo[(size_t)n * K + k] = f2bf(v - bf2f(h));
}

__global__ void xconv_kernel(const float* __restrict__ x,
                             unsigned short* __restrict__ xh, unsigned short* __restrict__ xl,
                             unsigned short* __restrict__ nh, unsigned short* __restrict__ nl) {
  int i = blockIdx.x * 256 + threadIdx.x;
  if (i < NN * DD) {
    float v = x[i];
    unsigned short h = f2bf(v), l = f2bf(v - bf2f(h));
    xh[i] = h; xl[i] = l; nh[i] = h; nl[i] = l;
  }
}

__global__ void deg_kernel(const int* __restrict__ ei, float* __restrict__ deg) {
  int e = blockIdx.x * 256 + threadIdx.x;
  if (e < NE) atomicAdd(&deg[ei[NE + e]], 1.0f);
}

__global__ void inv_kernel(const float* __restrict__ deg, float* __restrict__ idg) {
  int n = blockIdx.x * 256 + threadIdx.x;
  if (n < NN) idg[n] = 1.0f / fmaxf(deg[n], 1.0f);
}

// ---------------- per-node partial pre-activation GEMM ----------------
// psum layout (vectorized gathers): addr = n*256 + wv*64 + lr*4 + ct, col = wv*64 + ct*16 + lr

template<int NCH, bool USE_NF>
__launch_bounds__(256, 2)
__global__ void nodepre_kernel(
    const unsigned short* __restrict__ xh, const unsigned short* __restrict__ xl,
    const unsigned short* __restrict__ nh, const unsigned short* __restrict__ nl,
    const unsigned short* __restrict__ w0h, const unsigned short* __restrict__ w0l,
    int ko0, int st0, float* __restrict__ out0,
    const unsigned short* __restrict__ w1h, const unsigned short* __restrict__ w1l,
    int ko1, int st1, float* __restrict__ out1,
    const unsigned short* __restrict__ w2h, const unsigned short* __restrict__ w2l,
    int ko2, int st2, float* __restrict__ out2)
{
  const int y = blockIdx.y;
  const unsigned short* Wh = (y == 0) ? w0h : (y == 1) ? w1h : w2h;
  const unsigned short* Wl = (y == 0) ? w0l : (y == 1) ? w1l : w2l;
  const int ko = (y == 0) ? ko0 : (y == 1) ? ko1 : ko2;
  const int st = (y == 0) ? st0 : (y == 1) ? st1 : st2;
  float* out = (y == 0) ? out0 : (y == 1) ? out1 : out2;

  const int tid = threadIdx.x;
  const int n0 = blockIdx.x * 64;
  const int lane = tid & 63, wv = tid >> 6;
  const int lr = lane & 15, kg = lane >> 4;
  int nr[4];
#pragma unroll
  for (int rt = 0; rt < 4; ++rt) {
    const int n = n0 + rt*16 + lr;
    nr[rt] = (n < NN) ? n : (NN - 1);
  }
  const floatx4 Z4 = {0.f, 0.f, 0.f, 0.f};
  floatx4 acc[4][4];
#pragma unroll
  for (int i = 0; i < 4; ++i)
#pragma unroll
    for (int j = 0; j < 4; ++j) acc[i][j] = Z4;

#pragma unroll
  for (int ch = 0; ch < NCH; ++ch) {
    bf16x8 ah[4], al[4], bh[4], bl[4];
#pragma unroll
    for (int rt = 0; rt < 4; ++rt) {
      if (USE_NF && ch >= 4) {
        const size_t off = (size_t)nr[rt] * DD + (ch - 4)*32 + kg*8;
        ah[rt] = ld_bf8(nh + off); al[rt] = ld_bf8(nl + off);
      } else {
        const size_t off = (size_t)nr[rt] * DD + ch*32 + kg*8;
        ah[rt] = ld_bf8(xh + off); al[rt] = ld_bf8(xl + off);
      }
    }
#pragma unroll
    for (int ct = 0; ct < 4; ++ct) {
      const size_t wo = (size_t)(wv*64 + ct*16 + lr) * st + ko + ch*32 + kg*8;
      bh[ct] = ld_bf8(Wh + wo); bl[ct] = ld_bf8(Wl + wo);
    }
#pragma unroll
    for (int rt = 0; rt < 4; ++rt)
#pragma unroll
      for (int ct = 0; ct < 4; ++ct) acc[rt][ct] = MFMA3(ah[rt], al[rt], bh[ct], bl[ct], acc[rt][ct]);
  }
#pragma unroll
  for (int ct = 0; ct < 4; ++ct) {
#pragma unroll
    for (int rt = 0; rt < 4; ++rt)
#pragma unroll
      for (int j = 0; j < 4; ++j) {
        const int n = n0 + rt*16 + kg*4 + j;
        if (n < NN) out[(size_t)n * HH + wv*64 + lr*4 + ct] = acc[rt][ct][j];
      }
  }
}

// ---------------- edge encoder (psum-seeded, vectorized gathers) ----------------

__launch_bounds__(256, 2)
__global__ void encoder_kernel(
    const float* __restrict__ ea,
    const int* __restrict__ ei,
    const float* __restrict__ pes,
    const float* __restrict__ pet,
    const unsigned short* __restrict__ w1h, const unsigned short* __restrict__ w1l,
    const float* __restrict__ b1,
    const unsigned short* __restrict__ w2h, const unsigned short* __restrict__ w2l,
    const float* __restrict__ b2,
    float* __restrict__ ief32, float* __restrict__ eff32)
{
  __shared__ unsigned short h_hi[EBE * 264];
  __shared__ unsigned short h_lo[EBE * 264];
  __shared__ int sidx[EBE];
  __shared__ int tidx[EBE];
  const int tid = threadIdx.x;
  const int e0 = blockIdx.x * EBE;
  if (tid < EBE) { sidx[tid] = ei[e0 + tid]; tidx[tid] = ei[NE + e0 + tid]; }
  __syncthreads();

  const int lane = tid & 63, wv = tid >> 6;
  const int lr = lane & 15, kg = lane >> 4;
  const floatx4 Z4 = {0.f, 0.f, 0.f, 0.f};

  floatx4 pse[4][4];
#pragma unroll
  for (int rt = 0; rt < 4; ++rt)
#pragma unroll
    for (int j = 0; j < 4; ++j) {
      const int row = rt*16 + kg*4 + j;
      const floatx4 a = *(const floatx4*)(pes + (size_t)sidx[row] * HH + wv*64 + lr*4);
      const floatx4 b = *(const floatx4*)(pet + (size_t)tidx[row] * HH + wv*64 + lr*4);
      pse[rt][j] = a + b;
    }

  floatx4 acc[4][4];
#pragma unroll
  for (int i = 0; i < 4; ++i)
#pragma unroll
    for (int j = 0; j < 4; ++j) acc[i][j] = Z4;
#pragma unroll
  for (int sub = 0; sub < 4; ++sub) {
    const int off = sub*32 + kg*8;
    bf16x8 ah[4], al[4], bh[4], bl[4];
#pragma unroll
    for (int rt = 0; rt < 4; ++rt)
      split8(ea + (size_t)(e0 + rt*16 + lr) * DD + off, ah[rt], al[rt]);
#pragma unroll
    for (int ct = 0; ct < 4; ++ct) {
      const size_t wo = (size_t)(wv*64 + ct*16 + lr) * 384 + 256 + off;
      bh[ct] = ld_bf8(w1h + wo); bl[ct] = ld_bf8(w1l + wo);
    }
#pragma unroll
    for (int rt = 0; rt < 4; ++rt)
#pragma unroll
      for (int ct = 0; ct < 4; ++ct) acc[rt][ct] = MFMA3(ah[rt], al[rt], bh[ct], bl[ct], acc[rt][ct]);
  }
#pragma unroll
  for (int ct = 0; ct < 4; ++ct) {
    const int col = wv*64 + ct*16 + lr;
    const float bias = b1[col];
#pragma unroll
    for (int rt = 0; rt < 4; ++rt)
#pragma unroll
      for (int j = 0; j < 4; ++j) {
        const float v = fmaxf(acc[rt][ct][j] + bias + pse[rt][j][ct], 0.f);
        const unsigned short hh = f2bf(v);
        const int idx = (rt*16 + kg*4 + j) * 264 + col;
        h_hi[idx] = hh;
        h_lo[idx] = f2bf(v - bf2f(hh));
      }
  }
  __syncthreads();

  floatx4 acc2[4][2];
#pragma unroll
  for (int i = 0; i < 4; ++i) { acc2[i][0] = Z4; acc2[i][1] = Z4; }
#pragma unroll
  for (int ch = 0; ch < 8; ++ch) {
    bf16x8 ah[4], al[4], bh[2], bl[2];
#pragma unroll
    for (int rt = 0; rt < 4; ++rt) {
      const int idx = (rt*16 + lr) * 264 + ch*32 + kg*8;
      ah[rt] = ld_bf8(&h_hi[idx]); al[rt] = ld_bf8(&h_lo[idx]);
    }
#pragma unroll
    for (int c2 = 0; c2 < 2; ++c2) {
      const size_t wo = (size_t)(wv*32 + c2*16 + lr) * 256 + ch*32 + kg*8;
      bh[c2] = ld_bf8(w2h + wo); bl[c2] = ld_bf8(w2l + wo);
    }
#pragma unroll
    for (int rt = 0; rt < 4; ++rt)
#pragma unroll
      for (int c2 = 0; c2 < 2; ++c2) acc2[rt][c2] = MFMA3(ah[rt], al[rt], bh[c2], bl[c2], acc2[rt][c2]);
  }
#pragma unroll
  for (int c2 = 0; c2 < 2; ++c2) {
    const int col = wv*32 + c2*16 + lr;
    const float bias = b2[col];
#pragma unroll
    for (int rt = 0; rt < 4; ++rt)
#pragma unroll
      for (int j = 0; j < 4; ++j) {
        const float fv = acc2[rt][c2][j] + bias;
        const size_t idx = (size_t)(e0 + rt*16 + kg*4 + j) * DD + col;
        ief32[idx] = fv;
        eff32[idx] = fv;
      }
  }
}

// ---------------- fused per-iteration edge kernel ----------------
// EB=64 (rt=4), single time-shared hi/lo LDS buffer (h_edge -> eraw -> h_msg),
// 68 KB LDS -> 2 blocks/CU, no tail. s_setprio(1) around MFMA clusters (T5).

__launch_bounds__(256, 2)
__global__ void edge_iter_kernel(
    const float* __restrict__ ief32,
    float* __restrict__ eff32,
    const int* __restrict__ ei,
    const float* __restrict__ pse_,
    const float* __restrict__ pte_,
    const float* __restrict__ psm_,
    const unsigned short* __restrict__ ew1h, const unsigned short* __restrict__ ew1l,
    const float* __restrict__ eb1,
    const unsigned short* __restrict__ ew2h, const unsigned short* __restrict__ ew2l,
    const float* __restrict__ eb2,
    const unsigned short* __restrict__ mw1h, const unsigned short* __restrict__ mw1l,
    const float* __restrict__ mb1,
    const unsigned short* __restrict__ mw2h, const unsigned short* __restrict__ mw2l,
    const float* __restrict__ mb2,
    const float* __restrict__ lng, const float* __restrict__ lnb,
    float* __restrict__ agg,
    float* __restrict__ out_edge,
    int write_out)
{
  __shared__ unsigned short bufh[EB * 264];
  __shared__ unsigned short bufl[EB * 264];
  __shared__ int sidx[EB];
  __shared__ int tidx[EB];

  const int tid = threadIdx.x;
  const int e0 = blockIdx.x * EB;
  if (tid < EB) {
    sidx[tid] = ei[e0 + tid];
    tidx[tid] = ei[NE + e0 + tid];
  }
  __syncthreads();

  const int lane = tid & 63, wv = tid >> 6;
  const int lr = lane & 15, kg = lane >> 4;
  const floatx4 Z4 = {0.f, 0.f, 0.f, 0.f};

  // ===== psum gathers (edge-MLP seed, vectorized) =====
  floatx4 pse[4][4];
#pragma unroll
  for (int rt = 0; rt < 4; ++rt)
#pragma unroll
    for (int j = 0; j < 4; ++j) {
      const int row = rt*16 + kg*4 + j;
      const floatx4 a = *(const floatx4*)(pse_ + (size_t)sidx[row] * HH + wv*64 + lr*4);
      const floatx4 b = *(const floatx4*)(pte_ + (size_t)tidx[row] * HH + wv*64 + lr*4);
      pse[rt][j] = a + b;
    }

  // ===== P2: edge MLP layer 1, edge_c part (K=256: ie | ef) =====
  floatx4 acc[4][4];
#pragma unroll
  for (int i = 0; i < 4; ++i)
#pragma unroll
    for (int j = 0; j < 4; ++j) acc[i][j] = Z4;

#pragma unroll
  for (int seg = 0; seg < 2; ++seg) {
    const float* fb[4];
#pragma unroll
    for (int rt = 0; rt < 4; ++rt) {
      const size_t e = (size_t)(e0 + rt*16 + lr) * DD;
      fb[rt] = (seg == 0) ? ief32 + e : eff32 + e;
    }
#pragma unroll
    for (int sub = 0; sub < 4; ++sub) {
      const int off = sub*32 + kg*8;
      bf16x8 ah[4], al[4], bh[4], bl[4];
#pragma unroll
      for (int rt = 0; rt < 4; ++rt) split8(fb[rt] + off, ah[rt], al[rt]);
#pragma unroll
      for (int ct = 0; ct < 4; ++ct) {
        const size_t wo = (size_t)(wv*64 + ct*16 + lr) * 768 + 512 + seg*128 + off;
        bh[ct] = ld_bf8(ew1h + wo); bl[ct] = ld_bf8(ew1l + wo);
      }
      __builtin_amdgcn_s_setprio(1);
#pragma unroll
      for (int rt = 0; rt < 4; ++rt)
#pragma unroll
        for (int ct = 0; ct < 4; ++ct) acc[rt][ct] = MFMA3(ah[rt], al[rt], bh[ct], bl[ct], acc[rt][ct]);
      __builtin_amdgcn_s_setprio(0);
    }
  }
  // h_edge write (stride 264)
#pragma unroll
  for (int ct = 0; ct < 4; ++ct) {
    const int col = wv*64 + ct*16 + lr;
    const float bias = eb1[col];
#pragma unroll
    for (int rt = 0; rt < 4; ++rt)
#pragma unroll
      for (int j = 0; j < 4; ++j) {
        const float v = fmaxf(acc[rt][ct][j] + bias + pse[rt][j][ct], 0.f);
        const unsigned short hh = f2bf(v);
        const int idx = (rt*16 + kg*4 + j) * 264 + col;
        bufh[idx] = hh;
        bufl[idx] = f2bf(v - bf2f(hh));
      }
  }
  __syncthreads();   // h_edge visible

  // ===== P5: edge MLP layer 2 (reads h_edge) -> acc2 registers =====
  floatx4 acc2[4][2];
#pragma unroll
  for (int i = 0; i < 4; ++i) { acc2[i][0] = Z4; acc2[i][1] = Z4; }
#pragma unroll
  for (int ch = 0; ch < 8; ++ch) {
    bf16x8 ah[4], al[4], bh[2], bl[2];
#pragma unroll
    for (int rt = 0; rt < 4; ++rt) {
      const int idx = (rt*16 + lr) * 264 + ch*32 + kg*8;
      ah[rt] = ld_bf8(&bufh[idx]); al[rt] = ld_bf8(&bufl[idx]);
    }
#pragma unroll
    for (int c2 = 0; c2 < 2; ++c2) {
      const size_t wo = (size_t)(wv*32 + c2*16 + lr) * 256 + ch*32 + kg*8;
      bh[c2] = ld_bf8(ew2h + wo); bl[c2] = ld_bf8(ew2l + wo);
    }
    __builtin_amdgcn_s_setprio(1);
#pragma unroll
    for (int rt = 0; rt < 4; ++rt)
#pragma unroll
      for (int c2 = 0; c2 < 2; ++c2) acc2[rt][c2] = MFMA3(ah[rt], al[rt], bh[c2], bl[c2], acc2[rt][c2]);
    __builtin_amdgcn_s_setprio(0);
  }
  __syncthreads();   // all h_edge reads done; buffer free

  // eraw write (stride 136)
#pragma unroll
  for (int c2 = 0; c2 < 2; ++c2) {
    const int col = wv*32 + c2*16 + lr;
    const float bias = eb2[col];
#pragma unroll
    for (int rt = 0; rt < 4; ++rt)
#pragma unroll
      for (int j = 0; j < 4; ++j) {
        const float v = acc2[rt][c2][j] + bias;
        const unsigned short hh = f2bf(v);
        const int idx = (rt*16 + kg*4 + j) * 136 + col;
        bufh[idx] = hh;
        bufl[idx] = f2bf(v - bf2f(hh));
      }
  }
  __syncthreads();   // eraw visible

  // ===== P6: msg MLP layer 1, eraw part (K=128) + psrc_m seed (vectorized) =====
  floatx4 psm[4][4];
#pragma unroll
  for (int rt = 0; rt < 4; ++rt)
#pragma unroll
    for (int j = 0; j < 4; ++j) {
      const int row = rt*16 + kg*4 + j;
      psm[rt][j] = *(const floatx4*)(psm_ + (size_t)sidx[row] * HH + wv*64 + lr*4);
    }

  floatx4 accm[4][4];
#pragma unroll
  for (int i = 0; i < 4; ++i)
#pragma unroll
    for (int j = 0; j < 4; ++j) accm[i][j] = Z4;
#pragma unroll
  for (int sub = 0; sub < 4; ++sub) {
    const int off = sub*32 + kg*8;
    bf16x8 ah[4], al[4], bh[4], bl[4];
#pragma unroll
    for (int rt = 0; rt < 4; ++rt) {
      const int idx = (rt*16 + lr) * 136 + off;
      ah[rt] = ld_bf8(&bufh[idx]); al[rt] = ld_bf8(&bufl[idx]);
    }
#pragma unroll
    for (int ct = 0; ct < 4; ++ct) {
      const size_t wo = (size_t)(wv*64 + ct*16 + lr) * 384 + 256 + off;
      bh[ct] = ld_bf8(mw1h + wo); bl[ct] = ld_bf8(mw1l + wo);
    }
    __builtin_amdgcn_s_setprio(1);
#pragma unroll
    for (int rt = 0; rt < 4; ++rt)
#pragma unroll
      for (int ct = 0; ct < 4; ++ct) accm[rt][ct] = MFMA3(ah[rt], al[rt], bh[ct], bl[ct], accm[rt][ct]);
    __builtin_amdgcn_s_setprio(0);
  }

  // ===== residual + LayerNorm (reads eraw from LDS + ief32) -> eff32 (+ d_out) =====
  {
    const int row = tid >> 2, sub = tid & 3;   // 64 rows x 4 lanes, 32 cols each
    const size_t e = (size_t)(e0 + row);
    float v[32];
    float s = 0.f, ss = 0.f;
#pragma unroll
    for (int c8 = 0; c8 < 4; ++c8) {
      const int li = row * 136 + sub*32 + c8*8;
      ushort8 rh = *(const ushort8*)&bufh[li];
      ushort8 rl = *(const ushort8*)&bufl[li];
      const float* ip = &ief32[e * DD + sub*32 + c8*8];
      floatx4 i0 = *(const floatx4*)ip;
      floatx4 i1 = *(const floatx4*)(ip + 4);
#pragma unroll
      for (int k = 0; k < 4; ++k) {
        float v0 = (bf2f(rh[k]) + bf2f(rl[k])) + i0[k];
        float v1 = (bf2f(rh[k+4]) + bf2f(rl[k+4])) + i1[k];
        v[c8*8 + k] = v0; v[c8*8 + 4 + k] = v1;
        s += v0 + v1; ss += v0*v0 + v1*v1;
      }
    }
    s  += __shfl_xor(s, 1);  s  += __shfl_xor(s, 2);
    ss += __shfl_xor(ss, 1); ss += __shfl_xor(ss, 2);
    const float mu  = s * (1.f/128.f);
    const float var = ss * (1.f/128.f) - mu * mu;
    const float inv = rsqrtf(fmaxf(var, 0.f) + 1e-5f);
#pragma unroll
    for (int c8 = 0; c8 < 4; ++c8) {
      floatx4 o0, o1;
#pragma unroll
      for (int k = 0; k < 8; ++k) {
        const int col = sub*32 + c8*8 + k;
        const float o = (v[c8*8 + k] - mu) * inv * lng[col] + lnb[col];
        if (k < 4) o0[k] = o; else o1[k-4] = o;
      }
      *(floatx4*)&eff32[e * DD + sub*32 + c8*8] = o0;
      *(floatx4*)&eff32[e * DD + sub*32 + c8*8 + 4] = o1;
      if (write_out) {
        *(floatx4*)&out_edge[e * DD + sub*32 + c8*8] = o0;
        *(floatx4*)&out_edge[e * DD + sub*32 + c8*8 + 4] = o1;
      }
    }
  }
  __syncthreads();   // all eraw reads (P6 + LN) done; buffer free

  // h_msg write (stride 264)
#pragma unroll
  for (int ct = 0; ct < 4; ++ct) {
    const int col = wv*64 + ct*16 + lr;
    const float bias = mb1[col];
#pragma unroll
    for (int rt = 0; rt < 4; ++rt)
#pragma unroll
      for (int j = 0; j < 4; ++j) {
        const float v = fmaxf(accm[rt][ct][j] + bias + psm[rt][j][ct], 0.f);
        const unsigned short hh = f2bf(v);
        const int idx = (rt*16 + kg*4 + j) * 264 + col;
        bufh[idx] = hh;
        bufl[idx] = f2bf(v - bf2f(hh));
      }
  }
  __syncthreads();   // h_msg visible

  // ===== P7: msg MLP layer 2 + atomic scatter =====
  floatx4 accq[4][2];
#pragma unroll
  for (int i = 0; i < 4; ++i) { accq[i][0] = Z4; accq[i][1] = Z4; }
#pragma unroll
  for (int ch = 0; ch < 8; ++ch) {
    bf16x8 ah[4], al[4], bh[2], bl[2];
#pragma unroll
    for (int rt = 0; rt < 4; ++rt) {
      const int idx = (rt*16 + lr) * 264 + ch*32 + kg*8;
      ah[rt] = ld_bf8(&bufh[idx]); al[rt] = ld_bf8(&bufl[idx]);
    }
#pragma unroll
    for (int c2 = 0; c2 < 2; ++c2) {
      const size_t wo = (size_t)(wv*32 + c2*16 + lr) * 256 + ch*32 + kg*8;
      bh[c2] = ld_bf8(mw2h + wo); bl[c2] = ld_bf8(mw2l + wo);
    }
    __builtin_amdgcn_s_setprio(1);
#pragma unroll
    for (int rt = 0; rt < 4; ++rt)
#pragma unroll
      for (int c2 = 0; c2 < 2; ++c2) accq[rt][c2] = MFMA3(ah[rt], al[rt], bh[c2], bl[c2], accq[rt][c2]);
    __builtin_amdgcn_s_setprio(0);
  }
#pragma unroll
  for (int c2 = 0; c2 < 2; ++c2) {
    const int col = wv*32 + c2*16 + lr;
    const float bias = mb2[col];
#pragma unroll
    for (int rt = 0; rt < 4; ++rt)
#pragma unroll
      for (int j = 0; j < 4; ++j) {
        const int row = rt*16 + kg*4 + j;
        atomicAdd(&agg[(size_t)tidx[row] * DD + col], accq[rt][c2][j] + bias);
      }
  }
}

// ---------------- node update ----------------

__launch_bounds__(256, 2)
__global__ void node_update_kernel(
    const float* __restrict__ agg, const float* __restrict__ idg,
    const unsigned short* __restrict__ nwh, const unsigned short* __restrict__ nwl,
    const float* __restrict__ nb,
    const float* __restrict__ x,
    const float* __restrict__ lng, const float* __restrict__ lnb,
    float* __restrict__ out_node,
    unsigned short* __restrict__ nh, unsigned short* __restrict__ nl,
    int write_out)
{
  __shared__ unsigned short a_hi[64 * 136];
  __shared__ unsigned short a_lo[64 * 136];
  __shared__ float o_lds[64 * 132];
  const int tid = threadIdx.x;
  const int n0 = blockIdx.x * 64;
  const int row = tid >> 2, sub = tid & 3;
  const int n = n0 + row;
  {
    const float s = (n < NN) ? idg[n] : 0.f;
#pragma unroll
    for (int c4 = 0; c4 < 8; ++c4) {
      floatx4 v = {0.f, 0.f, 0.f, 0.f};
      if (n < NN) v = *(const floatx4*)&agg[(size_t)n * DD + sub*32 + c4*4];
#pragma unroll
      for (int k = 0; k < 4; ++k) {
        const float f = v[k] * s;
        const unsigned short hh = f2bf(f);
        const int idx = row * 136 + sub*32 + c4*4 + k;
        a_hi[idx] = hh;
        a_lo[idx] = f2bf(f - bf2f(hh));
      }
    }
  }
  __syncthreads();

  const int lane = tid & 63, wv = tid >> 6;
  const int lr = lane & 15, kg = lane >> 4;
  const floatx4 Z4 = {0.f, 0.f, 0.f, 0.f};
  floatx4 acc[4][2];
#pragma unroll
  for (int i = 0; i < 4; ++i) { acc[i][0] = Z4; acc[i][1] = Z4; }
#pragma unroll
  for (int ch = 0; ch < 4; ++ch) {
    bf16x8 ah[4], al[4], bh[2], bl[2];
#pragma unroll
    for (int rt = 0; rt < 4; ++rt) {
      const int idx = (rt*16 + lr) * 136 + ch*32 + kg*8;
      ah[rt] = ld_bf8(&a_hi[idx]); al[rt] = ld_bf8(&a_lo[idx]);
    }
#pragma unroll
    for (int c2 = 0; c2 < 2; ++c2) {
      const size_t wo = (size_t)(wv*32 + c2*16 + lr) * DD + ch*32 + kg*8;
      bh[c2] = ld_bf8(nwh + wo); bl[c2] = ld_bf8(nwl + wo);
    }
#pragma unroll
    for (int rt = 0; rt < 4; ++rt)
#pragma unroll
      for (int c2 = 0; c2 < 2; ++c2) acc[rt][c2] = MFMA3(ah[rt], al[rt], bh[c2], bl[c2], acc[rt][c2]);
  }
#pragma unroll
  for (int c2 = 0; c2 < 2; ++c2) {
    const int col = wv*32 + c2*16 + lr;
    const float bias = nb[col];
#pragma unroll
    for (int rt = 0; rt < 4; ++rt)
#pragma unroll
      for (int j = 0; j < 4; ++j)
        o_lds[(rt*16 + kg*4 + j) * 132 + col] = acc[rt][c2][j] + bias;
  }
  __syncthreads();

  if (n < NN) {
    float v[32];
    float s = 0.f, ss = 0.f;
#pragma unroll
    for (int c4 = 0; c4 < 8; ++c4) {
      floatx4 xa = *(const floatx4*)&x[(size_t)n * DD + sub*32 + c4*4];
#pragma unroll
      for (int k = 0; k < 4; ++k) {
        const float val = o_lds[row * 132 + sub*32 + c4*4 + k] + xa[k];
        v[c4*4 + k] = val; s += val; ss += val * val;
      }
    }
    s  += __shfl_xor(s, 1);  s  += __shfl_xor(s, 2);
    ss += __shfl_xor(ss, 1); ss += __shfl_xor(ss, 2);
    const float mu  = s * (1.f/128.f);
    const float var = ss * (1.f/128.f) - mu * mu;
    const float inv = rsqrtf(fmaxf(var, 0.f) + 1e-5f);
#pragma unroll
    for (int c8 = 0; c8 < 4; ++c8) {
      floatx4 o0, o1; ushort8 oh, ol;
#pragma unroll
      for (int k = 0; k < 8; ++k) {
        const int col = sub*32 + c8*8 + k;
        const float o = (v[c8*8 + k] - mu) * inv * lng[col] + lnb[col];
        if (k < 4) o0[k] = o; else o1[k-4] = o;
        const unsigned short hh = f2bf(o);
        oh[k] = hh;
        ol[k] = f2bf(o - bf2f(hh));
      }
      if (write_out) {
        *(floatx4*)&out_node[(size_t)n * DD + sub*32 + c8*8] = o0;
        *(floatx4*)&out_node[(size_t)n * DD + sub*32 + c8*8 + 4] = o1;
      }
      *(ushort8*)&nh[(size_t)n * DD + sub*32 + c8*8] = oh;
      *(ushort8*)&nl[(size_t)n * DD + sub*32 + c8*8] = ol;
    }
  }
}

// ---------------- host launch ----------------

extern "C" void kernel_launch(void* const* d_in, const int* in_sizes, int n_in,
                              void* d_out, int out_size, void* d_ws, size_t ws_size,
                              hipStream_t stream) {
  (void)in_sizes; (void)n_in; (void)out_size; (void)ws_size;

  const float* x      = (const float*)d_in[0];
  const float* ea     = (const float*)d_in[1];
  const int*   ei     = (const int*)d_in[2];
  const float* enc_w1 = (const float*)d_in[3];
  const float* enc_b1 = (const float*)d_in[4];
  const float* enc_w2 = (const float*)d_in[5];
  const float* enc_b2 = (const float*)d_in[6];
  const float* em_w1  = (const float*)d_in[7];
  const float* em_b1  = (const float*)d_in[8];
  const float* em_w2  = (const float*)d_in[9];
  const float* em_b2  = (const float*)d_in[10];
  const float* nm_w1  = (const float*)d_in[11];
  const float* nm_b1  = (const float*)d_in[12];
  const float* nm_w2  = (const float*)d_in[13];
  const float* nm_b2  = (const float*)d_in[14];
  const float* no_w   = (const float*)d_in[15];
  const float* no_b   = (const float*)d_in[16];
  const float* nlng   = (const float*)d_in[17];
  const float* nlnb   = (const float*)d_in[18];
  const float* elng   = (const float*)d_in[19];
  const float* elnb   = (const float*)d_in[20];

  float* out_node = (float*)d_out;
  float* ief32    = out_node + (size_t)NN * DD;  // f32 init_edge; final edge output overwrites

  char* p = (char*)d_ws;
  auto alloc = [&](size_t bytes) -> void* {
    void* r = (void*)p;
    p += (bytes + 255) & ~(size_t)255;
    return r;
  };
  unsigned short* xb_h = (unsigned short*)alloc((size_t)NN * DD * 2);
  unsigned short* xb_l = (unsigned short*)alloc((size_t)NN * DD * 2);
  unsigned short* nf_h = (unsigned short*)alloc((size_t)NN * DD * 2);
  unsigned short* nf_l = (unsigned short*)alloc((size_t)NN * DD * 2);
  float*          eff32 = (float*)alloc((size_t)NE * DD * 4);
  float*          agg  = (float*)alloc((size_t)NN * DD * 4);
  float*          deg  = (float*)alloc((size_t)NN * 4);
  float*          idg  = (float*)alloc((size_t)NN * 4);
  float*          psrc_e = (float*)alloc((size_t)NN * HH * 4);
  float*          ptgt_e = (float*)alloc((size_t)NN * HH * 4);
  float*          psrc_m = (float*)alloc((size_t)NN * HH * 4);
  unsigned short* cw1h = (unsigned short*)alloc((size_t)384 * 256 * 2);
  unsigned short* cw1l = (unsigned short*)alloc((size_t)384 * 256 * 2);
  unsigned short* cw2h = (unsigned short*)alloc((size_t)256 * 128 * 2);
  unsigned short* cw2l = (unsigned short*)alloc((size_t)256 * 128 * 2);
  unsigned short* ew1h = (unsigned short*)alloc((size_t)768 * 256 * 2);
  unsigned short* ew1l = (unsigned short*)alloc((size_t)768 * 256 * 2);
  unsigned short* ew2h = (unsigned short*)alloc((size_t)256 * 128 * 2);
  unsigned short* ew2l = (unsigned short*)alloc((size_t)256 * 128 * 2);
  unsigned short* mw1h = (unsigned short*)alloc((size_t)384 * 256 * 2);
  unsigned short* mw1l = (unsigned short*)alloc((size_t)384 * 256 * 2);
  unsigned short* mw2h = (unsigned short*)alloc((size_t)256 * 128 * 2);
  unsigned short* mw2l = (unsigned short*)alloc((size_t)256 * 128 * 2);
  unsigned short* nwh  = (unsigned short*)alloc((size_t)128 * 128 * 2);
  unsigned short* nwl  = (unsigned short*)alloc((size_t)128 * 128 * 2);

  wconv_kernel<<<(384*256 + 255)/256, 256, 0, stream>>>(enc_w1, cw1h, cw1l, 384, 256);
  wconv_kernel<<<(256*128 + 255)/256, 256, 0, stream>>>(enc_w2, cw2h, cw2l, 256, 128);
  wconv_kernel<<<(768*256 + 255)/256, 256, 0, stream>>>(em_w1, ew1h, ew1l, 768, 256);
  wconv_kernel<<<(256*128 + 255)/256, 256, 0, stream>>>(em_w2, ew2h, ew2l, 256, 128);
  wconv_kernel<<<(384*256 + 255)/256, 256, 0, stream>>>(nm_w1, mw1h, mw1l, 384, 256);
  wconv_kernel<<<(256*128 + 255)/256, 256, 0, stream>>>(nm_w2, mw2h, mw2l, 256, 128);
  wconv_kernel<<<(128*128 + 255)/256, 256, 0, stream>>>(no_w, nwh, nwl, 128, 128);

  xconv_kernel<<<(NN*DD + 255)/256, 256, 0, stream>>>(x, xb_h, xb_l, nf_h, nf_l);

  hipMemsetAsync(deg, 0, (size_t)NN * 4, stream);
  deg_kernel<<<(NE + 255)/256, 256, 0, stream>>>(ei, deg);
  inv_kernel<<<(NN + 255)/256, 256, 0, stream>>>(deg, idg);

  nodepre_kernel<4, false><<<dim3(313, 2), 256, 0, stream>>>(
      xb_h, xb_l, nf_h, nf_l,
      cw1h, cw1l, 0,   384, psrc_e,
      cw1h, cw1l, 128, 384, ptgt_e,
      cw1h, cw1l, 0,   384, psrc_e);

  encoder_kernel<<<NE/EBE, 256, 0, stream>>>(ea, ei, psrc_e, ptgt_e,
                                             cw1h, cw1l, enc_b1, cw2h, cw2l, enc_b2,
                                             ief32, eff32);

  const int egrid = NE / EB;   // 5000 exact
  for (int it = 0; it < 3; ++it) {
    const int last = (it == 2) ? 1 : 0;
    nodepre_kernel<8, true><<<dim3(313, 3), 256, 0, stream>>>(
        xb_h, xb_l, nf_h, nf_l,
        ew1h, ew1l, 0,   768, psrc_e,
        ew1h, ew1l, 256, 768, ptgt_e,
        mw1h, mw1l, 0,   384, psrc_m);
    hipMemsetAsync(agg, 0, (size_t)NN * DD * 4, stream);
    edge_iter_kernel<<<egrid, 256, 0, stream>>>(
        ief32, eff32, ei, psrc_e, ptgt_e, psrc_m,
        ew1h, ew1l, em_b1, ew2h, ew2l, em_b2,
        mw1h, mw1l, nm_b1, mw2h, mw2l, nm_b2,
        elng, elnb, agg, ief32, last);
    node_update_kernel<<<(NN + 63)/64, 256, 0, stream>>>(
        agg, idg, nwh, nwl, no_b, x, nlng, nlnb, out_node, nf_h, nf_l, last);
  }
}